// Round 4
// baseline (180.452 us; speedup 1.0000x reference)
//
#include <hip/hip_runtime.h>

typedef __attribute__((ext_vector_type(8))) short frag8;     // 8 bf16 = 4 VGPRs
typedef __attribute__((ext_vector_type(4))) float f4;
typedef __attribute__((ext_vector_type(4))) unsigned int u4;
typedef __attribute__((ext_vector_type(2))) float f2;

namespace {
constexpr int T_STEPS = 25;
constexpr int IN_F    = 14;
constexpr int H       = 24;
constexpr int NSTEP   = 13;
constexpr int GRID_PERSIST = 2048;   // 8 blocks/CU x 256 CU; < reg-residency cap (~9)
// Pad-free M=96 layout (6 tiles of 16 rows):
//   tile t<4, row m      -> gate t,   unit m        (m = 0..15)
//   tile 4,  row m       -> gate m&3, unit 16+(m>>2)
//   tile 5,  row m       -> gate m&3, unit 20+(m>>2)
// C/D lane (q=lane>>4, col=lane&15) holds rows m=4q+r -> all 4 gates of units
// {4q+r (r=0..3), 16+q, 20+q} = 6 real units, no padding.
// Wh B-operand k-slot map (k = 8q'+j): j<4 -> unit 4q'+j; j=4 -> 16+q';
// j=5 -> 20+q'; j>=6 -> zero. A lane's OUTPUT units == its own B k-slots
// -> recurrent h stays in registers.
//
// Wx k-slot map (LDS-free): chosen so B-frag k-group q needs only the
// 8 contiguous bytes x[row][4q..4q+3] (hi AND lo of the same 4 floats):
//   q<3 : j0..3 -> W[f=4q+j] (x_hi slot),  j4..7 -> W[f=4q+(j-4)] (x_lo slot)
//   q==3: j0/j4 -> W[12], j1/j5 -> W[13], j2 -> bias_hi, j3 -> bias_lo,
//         j6..7 -> 0.   B supplies 1.0 at j2,j3 and 0 at j6,j7.
// -> every lane builds its B-fragment from two 8-byte global loads, no LDS.
//
// d_ws: shorts [0..12288): frags ((dir*2+set)*6+tile)*64+lane, 8 shorts.
//   Pre-scaled per gate: i,f,o rows * (-log2e), g rows * (2*log2e).
constexpr float LOG2E    = 1.4426950408889634f;
constexpr float TWOLOG2E = 2.8853900817779268f;
}

#if __has_builtin(__builtin_amdgcn_exp2f)
#define EXP2F(v) __builtin_amdgcn_exp2f(v)
#else
#define EXP2F(v) __expf(0.6931471805599453f * (v))
#endif

__device__ __forceinline__ unsigned short bf16_rne(float f) {
    unsigned int u = __float_as_uint(f);
    u += 0x7fff + ((u >> 16) & 1);
    return (unsigned short)(u >> 16);
}
__device__ __forceinline__ float bf16_to_f(unsigned short s) {
    return __uint_as_float(((unsigned int)s) << 16);
}
__device__ __forceinline__ float fast_rcp(float x) { return __builtin_amdgcn_rcpf(x); }

__global__ void pack_mfma(const float* __restrict__ wif, const float* __restrict__ whf,
                          const float* __restrict__ bif, const float* __restrict__ bhf,
                          const float* __restrict__ wib, const float* __restrict__ whb,
                          const float* __restrict__ bib, const float* __restrict__ bhb,
                          unsigned short* __restrict__ ws)
{
    const int gid = blockIdx.x * 256 + threadIdx.x;
    if (gid >= 1536) return;                 // 2 dir * 2 sets * 6 tiles * 64 lanes
    const int lane = gid & 63;
    const int tile = (gid >> 6) % 6;
    const int set  = (gid / 384) & 1;
    const int dir  = gid / 768;
    const int m = lane & 15, q = lane >> 4;  // A-frag: row-in-tile m, k = q*8+j
    // row -> (gate, unit)
    const int g = (tile < 4) ? tile : (m & 3);
    const int u_row = (tile < 4) ? m : ((tile == 4 ? 16 : 20) + (m >> 2));
    const float* Wx = dir ? wib : wif;
    const float* Wh = dir ? whb : whf;
    const float* bi = dir ? bib : bif;
    const float* bh = dir ? bhb : bhf;
    const int rowW = g * 24 + u_row;         // original weight row
    const float scale = (g == 2) ? TWOLOG2E : -LOG2E;   // g-gate vs i,f,o
    unsigned short vals[8];
    #pragma unroll
    for (int j = 0; j < 8; ++j) {
        unsigned short o = 0;
        if (set == 0) {
            // Wx k-map (see header comment)
            if (q < 3) {
                const int f = 4 * q + (j & 3);
                o = bf16_rne(scale * Wx[rowW * IN_F + f]);
            } else {
                if (j == 0 || j == 4)      o = bf16_rne(scale * Wx[rowW * IN_F + 12]);
                else if (j == 1 || j == 5) o = bf16_rne(scale * Wx[rowW * IN_F + 13]);
                else if (j == 2 || j == 3) {
                    const float b = scale * (bi[rowW] + bh[rowW]);
                    const unsigned short hi = bf16_rne(b);
                    o = (j == 2) ? hi : bf16_rne(b - bf16_to_f(hi));
                }
                // j == 6,7 -> 0
            }
        } else {
            const int k = q * 8 + j;
            const int j7 = k & 7, kq = k >> 3;
            int uh = -1;
            if (j7 < 4)       uh = kq * 4 + j7;
            else if (j7 == 4) uh = 16 + kq;
            else if (j7 == 5) uh = 20 + kq;
            if (uh >= 0) o = bf16_rne(scale * Wh[rowW * H + uh]);
        }
        vals[j] = o;
    }
    unsigned short* d = ws + (size_t)gid * 8;
    #pragma unroll
    for (int j = 0; j < 8; ++j) d[j] = vals[j];
}

// One LSTM step's nonlinear update for 6 units/lane from pre-scaled accs.
// i,f,o hold -a*log2e; g holds 2a*log2e.
// c' = (c*(1+ei)(1+eg) + (eg-1)(1+ef)) * rcp((1+ef)(1+ei)(1+eg))
// h  = (ec-1) * rcp((1+eo)(1+ec)),  ec = exp2(2c'*log2e)
__device__ __forceinline__ void lstm_gates(const f4* acc, f4& cv, float& c_s0, float& c_s1,
                                           f4& Hv, float& h_s0, float& h_s1,
                                           frag8& Bhh, frag8& Bhl)
{
    f4 EI, EF, EG, EO, EC;
    #pragma unroll
    for (int r = 0; r < 4; ++r) {
        EI[r] = EXP2F(acc[0][r]);
        EF[r] = EXP2F(acc[1][r]);
        EG[r] = EXP2F(acc[2][r]);
        EO[r] = EXP2F(acc[3][r]);
    }
    const f4 P  = (EI + 1.0f) * (EG + 1.0f);
    const f4 Df = P * (EF + 1.0f);
    f4 Rf;
    #pragma unroll
    for (int r = 0; r < 4; ++r) Rf[r] = fast_rcp(Df[r]);
    cv = (cv * P + (EG - 1.0f) * (EF + 1.0f)) * Rf;
    #pragma unroll
    for (int r = 0; r < 4; ++r) EC[r] = EXP2F(TWOLOG2E * cv[r]);
    const f4 Do = (EO + 1.0f) * (EC + 1.0f);
    f4 Ro;
    #pragma unroll
    for (int r = 0; r < 4; ++r) Ro[r] = fast_rcp(Do[r]);
    Hv = (EC - 1.0f) * Ro;

    float hs[2];
    float cs[2] = {c_s0, c_s1};
    #pragma unroll
    for (int s = 0; s < 2; ++s) {
        const float ei = EXP2F(acc[4 + s][0]);
        const float ef = EXP2F(acc[4 + s][1]);
        const float eg = EXP2F(acc[4 + s][2]);
        const float eo = EXP2F(acc[4 + s][3]);
        const float P2 = (1.0f + ei) * (1.0f + eg);
        const float cn = (cs[s] * P2 + (eg - 1.0f) * (1.0f + ef))
                         * fast_rcp(P2 * (1.0f + ef));
        cs[s] = cn;
        const float ec = EXP2F(TWOLOG2E * cn);
        hs[s] = (ec - 1.0f) * fast_rcp((1.0f + eo) * (1.0f + ec));
    }
    c_s0 = cs[0]; c_s1 = cs[1];
    h_s0 = hs[0]; h_s1 = hs[1];

    // pack h -> own B-frag k-slots {8q+j}: j0..3 = units 4q+j, j4 = 16+q,
    // j5 = 20+q, j6..7 = zero-weight slots (any value)
    f4 Hl;
    #pragma unroll
    for (int r = 0; r < 4; ++r)
        Hl[r] = Hv[r] - __uint_as_float(__float_as_uint(Hv[r]) & 0xFFFF0000u);
    const float hl4 = hs[0] - __uint_as_float(__float_as_uint(hs[0]) & 0xFFFF0000u);
    const float hl5 = hs[1] - __uint_as_float(__float_as_uint(hs[1]) & 0xFFFF0000u);
    const u4 uh4 = {
        __builtin_amdgcn_perm(__float_as_uint(Hv[1]), __float_as_uint(Hv[0]), 0x07060302u),
        __builtin_amdgcn_perm(__float_as_uint(Hv[3]), __float_as_uint(Hv[2]), 0x07060302u),
        __builtin_amdgcn_perm(__float_as_uint(hs[1]), __float_as_uint(hs[0]), 0x07060302u),
        0u};
    const u4 ul4 = {
        __builtin_amdgcn_perm(__float_as_uint(Hl[1]), __float_as_uint(Hl[0]), 0x07060302u),
        __builtin_amdgcn_perm(__float_as_uint(Hl[3]), __float_as_uint(Hl[2]), 0x07060302u),
        __builtin_amdgcn_perm(__float_as_uint(hl5), __float_as_uint(hl4), 0x07060302u),
        0u};
    Bhh = __builtin_bit_cast(frag8, uh4);
    Bhl = __builtin_bit_cast(frag8, ul4);
}

__global__ __launch_bounds__(128, 4)
void bilstm_mfma(const float* __restrict__ x, const unsigned short* __restrict__ wpk,
                 const float* __restrict__ head_w, const float* __restrict__ head_b,
                 float* __restrict__ out, int B)
{
    // h-exchange arena, double-buffered by iteration parity so a persistent
    // block's next-iteration h-writes can't race this iteration's head-reads.
    // region(par) = arena + par*3072; within region: wave*1536 + elem*96.
    __align__(16) __shared__ unsigned char arena[2 * 2 * 1536];

    const int tid  = threadIdx.x;
    const int wave = __builtin_amdgcn_readfirstlane(tid >> 6);   // 0 = fwd, 1 = bwd
    const int lane = tid & 63;
    const int q    = lane >> 4;
    const int col  = lane & 15;

    // resident weight A-fragments: 2 sets x 6 tiles = 48 VGPRs
    frag8 Aw[2][6];
    #pragma unroll
    for (int s = 0; s < 2; ++s)
        #pragma unroll
        for (int t = 0; t < 6; ++t)
            Aw[s][t] = ((const frag8*)wpk)[((wave * 2 + s) * 6 + t) * 64 + lane];

    // ---- direct global -> B-fragment x path (no LDS, no transpose) ----
    // lane (q,col) needs x[b0+col][t][4q..4q+3]; q==3 needs f12,f13 + bias.
    // q==3 loads bytes 40..55 ({f10,f11,f12,f13}) so all loads are 8B-aligned
    // in-bounds pairs; f12,f13 arrive in the second pair.
    const bool q3 = (q == 3);
    const unsigned int biasor = q3 ? 0x3F803F80u : 0u;   // bf16 {1.0,1.0} at j2,j3
    const int  boff  = q3 ? 40 : q * 16;
    const int  t0    = wave ? (T_STEPS - 1) : 0;
    const int  dstep = wave ? -(IN_F * 4) : (IN_F * 4);

    auto build_bx = [&](f2 la, f2 lb) -> frag8 {
        const float a0 = q3 ? lb.x : la.x;
        const float a1 = q3 ? lb.y : la.y;
        const float a2 = q3 ? 0.0f : lb.x;
        const float a3 = q3 ? 0.0f : lb.y;
        const float l0 = a0 - __uint_as_float(__float_as_uint(a0) & 0xFFFF0000u);
        const float l1 = a1 - __uint_as_float(__float_as_uint(a1) & 0xFFFF0000u);
        const float l2 = a2 - __uint_as_float(__float_as_uint(a2) & 0xFFFF0000u);
        const float l3 = a3 - __uint_as_float(__float_as_uint(a3) & 0xFFFF0000u);
        const u4 w = {
            __builtin_amdgcn_perm(__float_as_uint(a1), __float_as_uint(a0), 0x07060302u),
            __builtin_amdgcn_perm(__float_as_uint(a3), __float_as_uint(a2), 0x07060302u) | biasor,
            __builtin_amdgcn_perm(__float_as_uint(l1), __float_as_uint(l0), 0x07060302u),
            __builtin_amdgcn_perm(__float_as_uint(l3), __float_as_uint(l2), 0x07060302u)};
        return __builtin_bit_cast(frag8, w);
    };

    const f4 zc = {0.f, 0.f, 0.f, 0.f};
    const int nG = (B + 15) / 16;

    // ---- persistent grid-stride loop over batch-groups ----
    int par = 0;
    #pragma unroll 1
    for (int g = blockIdx.x; g < nG; g += gridDim.x, par ^= 1) {
        const int b0 = g * 16;
        const char* px = (const char*)x
                       + ((size_t)(b0 + col) * T_STEPS + t0) * (IN_F * 4) + boff;

        f4    cv = {0.f, 0.f, 0.f, 0.f};   // c of units 4q+r
        float c_s0 = 0.f, c_s1 = 0.f;      // c of units 16+q, 20+q
        f4    Hv;                          // h of units 4q+r (fp32, for head)
        float h_s0, h_s1;                  // h of units 16+q, 20+q
        frag8 Bhh, Bhl;                    // recurrent h as B-fragments

        // prologue: load step-0 x
        f2 la = *(const f2*)px;
        f2 lb = *(const f2*)(px + 8);
        px += dstep;

        // ---- step 0 (h = 0: x-product + bias rows only) ----
        {
            const frag8 Bx = build_bx(la, lb);
            la = *(const f2*)px; lb = *(const f2*)(px + 8); px += dstep;   // prefetch s=1
            f4 acc[6];
            #pragma unroll
            for (int t = 0; t < 6; ++t)
                acc[t] = __builtin_amdgcn_mfma_f32_16x16x32_bf16(Aw[0][t], Bx, zc, 0, 0, 0);
            lstm_gates(acc, cv, c_s0, c_s1, Hv, h_s0, h_s1, Bhh, Bhl);
        }

        // ---- steps 1..12: pure-register recurrence, x prefetched 1 step ahead ----
        #pragma unroll 1
        for (int s = 1; s < NSTEP; ++s) {
            const frag8 Bx = build_bx(la, lb);
            // prefetch s+1 (s==12 reads t=13 fwd / t=11 bwd: in-bounds, unused)
            la = *(const f2*)px; lb = *(const f2*)(px + 8); px += dstep;
            f4 acc[6];
            #pragma unroll
            for (int t = 0; t < 6; ++t) {
                acc[t] = __builtin_amdgcn_mfma_f32_16x16x32_bf16(Aw[0][t], Bx,  zc,     0, 0, 0);
                acc[t] = __builtin_amdgcn_mfma_f32_16x16x32_bf16(Aw[1][t], Bhh, acc[t], 0, 0, 0);
                acc[t] = __builtin_amdgcn_mfma_f32_16x16x32_bf16(Aw[1][t], Bhl, acc[t], 0, 0, 0);
            }
            lstm_gates(acc, cv, c_s0, c_s1, Hv, h_s0, h_s1, Bhh, Bhl);
        }

        // final h (fp32) -> own wave region of this parity's arena half
        unsigned char* region = arena + par * 3072;
        unsigned char* hbase  = region + wave * 1536;
        *(f4*)(hbase + col * 96 + q * 16) = Hv;                   // units 4q+r
        *(float*)(hbase + col * 96 + 64 + q * 4) = h_s0;          // unit 16+q
        *(float*)(hbase + col * 96 + 80 + q * 4) = h_s1;          // unit 20+q

        __syncthreads();   // only cross-wave point: head reads both directions' h

        if (tid < 64) {
            const int e = tid >> 2, cls = tid & 3;
            float acc = head_b[cls];
            const float* hf = (const float*)(region + e * 96);            // fwd
            const float* hb = (const float*)(region + 1536 + e * 96);     // bwd
            #pragma unroll
            for (int u = 0; u < H; ++u)
                acc += hf[u] * head_w[cls * 2 * H + u] + hb[u] * head_w[cls * 2 * H + H + u];
            out[(size_t)b0 * 4 + tid] = acc;
        }
        // no second barrier needed: next iteration writes the OTHER arena half;
        // this half is only re-written two iterations out, after the next
        // iteration's __syncthreads (which follows these head-reads).
    }
}

extern "C" void kernel_launch(void* const* d_in, const int* in_sizes, int n_in,
                              void* d_out, int out_size, void* d_ws, size_t ws_size,
                              hipStream_t stream)
{
    const float* x      = (const float*)d_in[0];
    const float* w_ih_f = (const float*)d_in[1];
    const float* w_hh_f = (const float*)d_in[2];
    const float* b_ih_f = (const float*)d_in[3];
    const float* b_hh_f = (const float*)d_in[4];
    const float* w_ih_b = (const float*)d_in[5];
    const float* w_hh_b = (const float*)d_in[6];
    const float* b_ih_b = (const float*)d_in[7];
    const float* b_hh_b = (const float*)d_in[8];
    const float* head_w = (const float*)d_in[9];
    const float* head_b = (const float*)d_in[10];
    float* out = (float*)d_out;
    unsigned short* ws = (unsigned short*)d_ws;

    const int B = in_sizes[0] / (T_STEPS * IN_F);
    const int nG = (B + 15) / 16;
    const int grid = nG < GRID_PERSIST ? nG : GRID_PERSIST;

    hipLaunchKernelGGL(pack_mfma, dim3(6), dim3(256), 0, stream,
                       w_ih_f, w_hh_f, b_ih_f, b_hh_f,
                       w_ih_b, w_hh_b, b_ih_b, b_hh_b, ws);
    hipLaunchKernelGGL(bilstm_mfma, dim3(grid), dim3(128), 0, stream,
                       x, ws, head_w, head_b, out, B);
}

// Round 5
// 178.966 us; speedup vs baseline: 1.0083x; 1.0083x over previous
//
#include <hip/hip_runtime.h>

typedef __attribute__((ext_vector_type(8))) short frag8;     // 8 bf16 = 4 VGPRs
typedef __attribute__((ext_vector_type(4))) float f4;
typedef __attribute__((ext_vector_type(4))) unsigned int u4;
typedef __attribute__((ext_vector_type(2))) float f2;

namespace {
constexpr int T_STEPS = 25;
constexpr int IN_F    = 14;
constexpr int H       = 24;
constexpr int NSTEP   = 13;
constexpr int GRID_PERSIST = 2048;   // 8 blocks/CU x 256 CU
// Pad-free M=96 layout (6 tiles of 16 rows):
//   tile t<4, row m      -> gate t,   unit m        (m = 0..15)
//   tile 4,  row m       -> gate m&3, unit 16+(m>>2)
//   tile 5,  row m       -> gate m&3, unit 20+(m>>2)
// C/D lane (q=lane>>4, col=lane&15) holds rows m=4q+r -> all 4 gates of units
// {4q+r (r=0..3), 16+q, 20+q} = 6 real units, no padding.
// Wh B-operand k-slot map (k = 8q'+j): j<4 -> unit 4q'+j; j=4 -> 16+q';
// j=5 -> 20+q'; j>=6 -> zero. A lane's OUTPUT units == its own B k-slots
// -> recurrent h stays in registers.
//
// Wx k-slot map (LDS-free): chosen so B-frag k-group q needs only the
// 8 contiguous bytes x[row][4q..4q+3] (hi AND lo of the same 4 floats):
//   q<3 : j0..3 -> W[f=4q+j] (x_hi slot),  j4..7 -> W[f=4q+(j-4)] (x_lo slot)
//   q==3: j0/j4 -> W[12], j1/j5 -> W[13], j2 -> bias_hi, j3 -> bias_lo,
//         j6..7 -> 0.   B supplies 1.0 at j2,j3 and 0 at j6,j7.
// -> every lane builds its B-fragment from two 8-byte global loads, no LDS.
// x loads are prefetched 4 steps deep (rotating register slots) to cover
// L3/HBM latency (~900 cyc) with ~4 step-times of slack.
//
// d_ws: shorts [0..12288): frags ((dir*2+set)*6+tile)*64+lane, 8 shorts.
//   Pre-scaled per gate: i,f,o rows * (-log2e), g rows * (2*log2e).
constexpr float LOG2E    = 1.4426950408889634f;
constexpr float TWOLOG2E = 2.8853900817779268f;
}

#if __has_builtin(__builtin_amdgcn_exp2f)
#define EXP2F(v) __builtin_amdgcn_exp2f(v)
#else
#define EXP2F(v) __expf(0.6931471805599453f * (v))
#endif

__device__ __forceinline__ unsigned short bf16_rne(float f) {
    unsigned int u = __float_as_uint(f);
    u += 0x7fff + ((u >> 16) & 1);
    return (unsigned short)(u >> 16);
}
__device__ __forceinline__ float bf16_to_f(unsigned short s) {
    return __uint_as_float(((unsigned int)s) << 16);
}
__device__ __forceinline__ float fast_rcp(float x) { return __builtin_amdgcn_rcpf(x); }

__global__ void pack_mfma(const float* __restrict__ wif, const float* __restrict__ whf,
                          const float* __restrict__ bif, const float* __restrict__ bhf,
                          const float* __restrict__ wib, const float* __restrict__ whb,
                          const float* __restrict__ bib, const float* __restrict__ bhb,
                          unsigned short* __restrict__ ws)
{
    const int gid = blockIdx.x * 256 + threadIdx.x;
    if (gid >= 1536) return;                 // 2 dir * 2 sets * 6 tiles * 64 lanes
    const int lane = gid & 63;
    const int tile = (gid >> 6) % 6;
    const int set  = (gid / 384) & 1;
    const int dir  = gid / 768;
    const int m = lane & 15, q = lane >> 4;  // A-frag: row-in-tile m, k = q*8+j
    // row -> (gate, unit)
    const int g = (tile < 4) ? tile : (m & 3);
    const int u_row = (tile < 4) ? m : ((tile == 4 ? 16 : 20) + (m >> 2));
    const float* Wx = dir ? wib : wif;
    const float* Wh = dir ? whb : whf;
    const float* bi = dir ? bib : bif;
    const float* bh = dir ? bhb : bhf;
    const int rowW = g * 24 + u_row;         // original weight row
    const float scale = (g == 2) ? TWOLOG2E : -LOG2E;   // g-gate vs i,f,o
    unsigned short vals[8];
    #pragma unroll
    for (int j = 0; j < 8; ++j) {
        unsigned short o = 0;
        if (set == 0) {
            // Wx k-map (see header comment)
            if (q < 3) {
                const int f = 4 * q + (j & 3);
                o = bf16_rne(scale * Wx[rowW * IN_F + f]);
            } else {
                if (j == 0 || j == 4)      o = bf16_rne(scale * Wx[rowW * IN_F + 12]);
                else if (j == 1 || j == 5) o = bf16_rne(scale * Wx[rowW * IN_F + 13]);
                else if (j == 2 || j == 3) {
                    const float b = scale * (bi[rowW] + bh[rowW]);
                    const unsigned short hi = bf16_rne(b);
                    o = (j == 2) ? hi : bf16_rne(b - bf16_to_f(hi));
                }
                // j == 6,7 -> 0
            }
        } else {
            const int k = q * 8 + j;
            const int j7 = k & 7, kq = k >> 3;
            int uh = -1;
            if (j7 < 4)       uh = kq * 4 + j7;
            else if (j7 == 4) uh = 16 + kq;
            else if (j7 == 5) uh = 20 + kq;
            if (uh >= 0) o = bf16_rne(scale * Wh[rowW * H + uh]);
        }
        vals[j] = o;
    }
    unsigned short* d = ws + (size_t)gid * 8;
    #pragma unroll
    for (int j = 0; j < 8; ++j) d[j] = vals[j];
}

// One LSTM step's nonlinear update for 6 units/lane from pre-scaled accs.
// i,f,o hold -a*log2e; g holds 2a*log2e.
// c' = (c*(1+ei)(1+eg) + (eg-1)(1+ef)) * rcp((1+ef)(1+ei)(1+eg))
// h  = (ec-1) * rcp((1+eo)(1+ec)),  ec = exp2(2c'*log2e)
__device__ __forceinline__ void lstm_gates(const f4* acc, f4& cv, float& c_s0, float& c_s1,
                                           f4& Hv, float& h_s0, float& h_s1,
                                           frag8& Bhh, frag8& Bhl)
{
    f4 EI, EF, EG, EO, EC;
    #pragma unroll
    for (int r = 0; r < 4; ++r) {
        EI[r] = EXP2F(acc[0][r]);
        EF[r] = EXP2F(acc[1][r]);
        EG[r] = EXP2F(acc[2][r]);
        EO[r] = EXP2F(acc[3][r]);
    }
    const f4 P  = (EI + 1.0f) * (EG + 1.0f);
    const f4 Df = P * (EF + 1.0f);
    f4 Rf;
    #pragma unroll
    for (int r = 0; r < 4; ++r) Rf[r] = fast_rcp(Df[r]);
    cv = (cv * P + (EG - 1.0f) * (EF + 1.0f)) * Rf;
    #pragma unroll
    for (int r = 0; r < 4; ++r) EC[r] = EXP2F(TWOLOG2E * cv[r]);
    const f4 Do = (EO + 1.0f) * (EC + 1.0f);
    f4 Ro;
    #pragma unroll
    for (int r = 0; r < 4; ++r) Ro[r] = fast_rcp(Do[r]);
    Hv = (EC - 1.0f) * Ro;

    float hs[2];
    float cs[2] = {c_s0, c_s1};
    #pragma unroll
    for (int s = 0; s < 2; ++s) {
        const float ei = EXP2F(acc[4 + s][0]);
        const float ef = EXP2F(acc[4 + s][1]);
        const float eg = EXP2F(acc[4 + s][2]);
        const float eo = EXP2F(acc[4 + s][3]);
        const float P2 = (1.0f + ei) * (1.0f + eg);
        const float cn = (cs[s] * P2 + (eg - 1.0f) * (1.0f + ef))
                         * fast_rcp(P2 * (1.0f + ef));
        cs[s] = cn;
        const float ec = EXP2F(TWOLOG2E * cn);
        hs[s] = (ec - 1.0f) * fast_rcp((1.0f + eo) * (1.0f + ec));
    }
    c_s0 = cs[0]; c_s1 = cs[1];
    h_s0 = hs[0]; h_s1 = hs[1];

    // pack h -> own B-frag k-slots {8q+j}: j0..3 = units 4q+j, j4 = 16+q,
    // j5 = 20+q, j6..7 = zero-weight slots (any value)
    f4 Hl;
    #pragma unroll
    for (int r = 0; r < 4; ++r)
        Hl[r] = Hv[r] - __uint_as_float(__float_as_uint(Hv[r]) & 0xFFFF0000u);
    const float hl4 = hs[0] - __uint_as_float(__float_as_uint(hs[0]) & 0xFFFF0000u);
    const float hl5 = hs[1] - __uint_as_float(__float_as_uint(hs[1]) & 0xFFFF0000u);
    const u4 uh4 = {
        __builtin_amdgcn_perm(__float_as_uint(Hv[1]), __float_as_uint(Hv[0]), 0x07060302u),
        __builtin_amdgcn_perm(__float_as_uint(Hv[3]), __float_as_uint(Hv[2]), 0x07060302u),
        __builtin_amdgcn_perm(__float_as_uint(hs[1]), __float_as_uint(hs[0]), 0x07060302u),
        0u};
    const u4 ul4 = {
        __builtin_amdgcn_perm(__float_as_uint(Hl[1]), __float_as_uint(Hl[0]), 0x07060302u),
        __builtin_amdgcn_perm(__float_as_uint(Hl[3]), __float_as_uint(Hl[2]), 0x07060302u),
        __builtin_amdgcn_perm(__float_as_uint(hl5), __float_as_uint(hl4), 0x07060302u),
        0u};
    Bhh = __builtin_bit_cast(frag8, uh4);
    Bhl = __builtin_bit_cast(frag8, ul4);
}

__global__ __launch_bounds__(128, 4)
void bilstm_mfma(const float* __restrict__ x, const unsigned short* __restrict__ wpk,
                 const float* __restrict__ head_w, const float* __restrict__ head_b,
                 float* __restrict__ out, int B)
{
    // h-exchange arena, double-buffered by iteration parity so a persistent
    // block's next-iteration h-writes can't race this iteration's head-reads.
    __align__(16) __shared__ unsigned char arena[2 * 2 * 1536];

    const int tid  = threadIdx.x;
    const int wave = __builtin_amdgcn_readfirstlane(tid >> 6);   // 0 = fwd, 1 = bwd
    const int lane = tid & 63;
    const int q    = lane >> 4;
    const int col  = lane & 15;

    // resident weight A-fragments: 2 sets x 6 tiles = 48 VGPRs
    frag8 Aw[2][6];
    #pragma unroll
    for (int s = 0; s < 2; ++s)
        #pragma unroll
        for (int t = 0; t < 6; ++t)
            Aw[s][t] = ((const frag8*)wpk)[((wave * 2 + s) * 6 + t) * 64 + lane];

    // ---- direct global -> B-fragment x path (no LDS, no transpose) ----
    // lane (q,col) needs x[b0+col][t][4q..4q+3]; q==3 needs f12,f13 + bias.
    // q==3 loads bytes 40..55 ({f10,f11,f12,f13}) so all loads are 8B-aligned
    // in-bounds pairs; f12,f13 arrive in the second pair.
    const bool q3 = (q == 3);
    const unsigned int biasor = q3 ? 0x3F803F80u : 0u;   // bf16 {1.0,1.0} at j2,j3
    const int  boff  = q3 ? 40 : q * 16;
    const int  t0    = wave ? (T_STEPS - 1) : 0;
    const int  dstep = wave ? -(IN_F * 4) : (IN_F * 4);

    auto build_bx = [&](f2 la, f2 lb) -> frag8 {
        const float a0 = q3 ? lb.x : la.x;
        const float a1 = q3 ? lb.y : la.y;
        const float a2 = q3 ? 0.0f : lb.x;
        const float a3 = q3 ? 0.0f : lb.y;
        const float l0 = a0 - __uint_as_float(__float_as_uint(a0) & 0xFFFF0000u);
        const float l1 = a1 - __uint_as_float(__float_as_uint(a1) & 0xFFFF0000u);
        const float l2 = a2 - __uint_as_float(__float_as_uint(a2) & 0xFFFF0000u);
        const float l3 = a3 - __uint_as_float(__float_as_uint(a3) & 0xFFFF0000u);
        const u4 w = {
            __builtin_amdgcn_perm(__float_as_uint(a1), __float_as_uint(a0), 0x07060302u),
            __builtin_amdgcn_perm(__float_as_uint(a3), __float_as_uint(a2), 0x07060302u) | biasor,
            __builtin_amdgcn_perm(__float_as_uint(l1), __float_as_uint(l0), 0x07060302u),
            __builtin_amdgcn_perm(__float_as_uint(l3), __float_as_uint(l2), 0x07060302u)};
        return __builtin_bit_cast(frag8, w);
    };

    const f4 zc = {0.f, 0.f, 0.f, 0.f};
    const int nG = (B + 15) / 16;

    // ---- persistent grid-stride loop over batch-groups ----
    int par = 0;
    #pragma unroll 1
    for (int g = blockIdx.x; g < nG; g += gridDim.x, par ^= 1) {
        const int b0 = g * 16;
        const char* px = (const char*)x
                       + ((size_t)(b0 + col) * T_STEPS + t0) * (IN_F * 4) + boff;

        f4    cv = {0.f, 0.f, 0.f, 0.f};   // c of units 4q+r
        float c_s0 = 0.f, c_s1 = 0.f;      // c of units 16+q, 20+q
        f4    Hv;                          // h of units 4q+r (fp32, for head)
        float h_s0, h_s1;                  // h of units 16+q, 20+q
        frag8 Bhh, Bhl;                    // recurrent h as B-fragments

        // ---- 4-deep rotating x prefetch: slot k holds step s with s&3==k ----
        // All slot indices are compile-time after unrolling (no scratch).
        f2 LA[4], LB[4];
        #pragma unroll
        for (int k = 0; k < 4; ++k) {
            LA[k] = *(const f2*)px;
            LB[k] = *(const f2*)(px + 8);
            px += dstep;
        }

        // ---- step 0 (h = 0: x-product + bias rows only) ----
        {
            const frag8 Bx = build_bx(LA[0], LB[0]);
            LA[0] = *(const f2*)px; LB[0] = *(const f2*)(px + 8); px += dstep; // step 4
            f4 acc[6];
            #pragma unroll
            for (int t = 0; t < 6; ++t)
                acc[t] = __builtin_amdgcn_mfma_f32_16x16x32_bf16(Aw[0][t], Bx, zc, 0, 0, 0);
            lstm_gates(acc, cv, c_s0, c_s1, Hv, h_s0, h_s1, Bhh, Bhl);
        }

        // ---- steps 1..12: pure-register recurrence, x prefetched 4 ahead ----
        // (loads for steps >12 read t<=16 fwd / t>=8 bwd: in-bounds, unused)
        #pragma unroll 4
        for (int s = 1; s < NSTEP; ++s) {
            const frag8 Bx = build_bx(LA[s & 3], LB[s & 3]);
            LA[s & 3] = *(const f2*)px; LB[s & 3] = *(const f2*)(px + 8); px += dstep;
            f4 acc[6];
            #pragma unroll
            for (int t = 0; t < 6; ++t) {
                acc[t] = __builtin_amdgcn_mfma_f32_16x16x32_bf16(Aw[0][t], Bx,  zc,     0, 0, 0);
                acc[t] = __builtin_amdgcn_mfma_f32_16x16x32_bf16(Aw[1][t], Bhh, acc[t], 0, 0, 0);
                acc[t] = __builtin_amdgcn_mfma_f32_16x16x32_bf16(Aw[1][t], Bhl, acc[t], 0, 0, 0);
            }
            lstm_gates(acc, cv, c_s0, c_s1, Hv, h_s0, h_s1, Bhh, Bhl);
        }

        // final h (fp32) -> own wave region of this parity's arena half
        unsigned char* region = arena + par * 3072;
        unsigned char* hbase  = region + wave * 1536;
        *(f4*)(hbase + col * 96 + q * 16) = Hv;                   // units 4q+r
        *(float*)(hbase + col * 96 + 64 + q * 4) = h_s0;          // unit 16+q
        *(float*)(hbase + col * 96 + 80 + q * 4) = h_s1;          // unit 20+q

        __syncthreads();   // only cross-wave point: head reads both directions' h

        if (tid < 64) {
            const int e = tid >> 2, cls = tid & 3;
            float acc = head_b[cls];
            const float* hf = (const float*)(region + e * 96);            // fwd
            const float* hb = (const float*)(region + 1536 + e * 96);     // bwd
            #pragma unroll
            for (int u = 0; u < H; ++u)
                acc += hf[u] * head_w[cls * 2 * H + u] + hb[u] * head_w[cls * 2 * H + H + u];
            out[(size_t)b0 * 4 + tid] = acc;
        }
        // next iteration writes the OTHER arena half; this half is re-written
        // two iterations out, after an intervening __syncthreads.
    }
}

extern "C" void kernel_launch(void* const* d_in, const int* in_sizes, int n_in,
                              void* d_out, int out_size, void* d_ws, size_t ws_size,
                              hipStream_t stream)
{
    const float* x      = (const float*)d_in[0];
    const float* w_ih_f = (const float*)d_in[1];
    const float* w_hh_f = (const float*)d_in[2];
    const float* b_ih_f = (const float*)d_in[3];
    const float* b_hh_f = (const float*)d_in[4];
    const float* w_ih_b = (const float*)d_in[5];
    const float* w_hh_b = (const float*)d_in[6];
    const float* b_ih_b = (const float*)d_in[7];
    const float* b_hh_b = (const float*)d_in[8];
    const float* head_w = (const float*)d_in[9];
    const float* head_b = (const float*)d_in[10];
    float* out = (float*)d_out;
    unsigned short* ws = (unsigned short*)d_ws;

    const int B = in_sizes[0] / (T_STEPS * IN_F);
    const int nG = (B + 15) / 16;
    const int grid = nG < GRID_PERSIST ? nG : GRID_PERSIST;

    hipLaunchKernelGGL(pack_mfma, dim3(6), dim3(256), 0, stream,
                       w_ih_f, w_hh_f, b_ih_f, b_hh_f,
                       w_ih_b, w_hh_b, b_ih_b, b_hh_b, ws);
    hipLaunchKernelGGL(bilstm_mfma, dim3(grid), dim3(128), 0, stream,
                       x, ws, head_w, head_b, out, B);
}

// Round 6
// 171.970 us; speedup vs baseline: 1.0493x; 1.0407x over previous
//
#include <hip/hip_runtime.h>

typedef __attribute__((ext_vector_type(8))) short frag8;     // 8 bf16 = 4 VGPRs
typedef __attribute__((ext_vector_type(4))) float f4;
typedef __attribute__((ext_vector_type(4))) unsigned int u4;
typedef __attribute__((ext_vector_type(2))) unsigned int u2;
typedef __attribute__((ext_vector_type(2))) float f2;

namespace {
constexpr int T_STEPS = 25;
constexpr int IN_F    = 14;
constexpr int H       = 24;
constexpr int NSTEP   = 13;
constexpr int STEP_B  = 512;               // 16 elems x 8 words x 4 B
constexpr int WAVE_REGION = 14 * STEP_B;   // 13 steps + 1 pad slot (prefetch overrun)
// Pad-free M=96 layout (6 tiles of 16 rows):
//   tile t<4, row m -> gate t, unit m ; tile 4/5 row m -> gate m&3, unit 16/20+(m>>2)
// C/D lane (q=lane>>4, col=lane&15) holds all 4 gates of units
// {4q+r (r=0..3), 16+q, 20+q} = 6 real units.
//
// MERGED 2-MFMA k-map (x folded into the Wh MFMAs' free slots):
// Both MFMAs m=0,1 share the Wh unit map at j=0..5 of each k-group q':
//   j<4 -> unit 4q'+j ; j=4 -> 16+q' ; j=5 -> 20+q'
//   (m=0 multiplies h_hi, m=1 multiplies h_lo; identical Wh weights)
// Slots j=6,7 carry Wx columns (x as single rne-bf16):
//   m=0: features {4q'+0, 4q'+1}           (q'=0..3 -> f 0,1 / 4,5 / 8,9 / 12,13)
//   m=1, q'<3: features {4q'+2, 4q'+3}     (f 2,3 / 6,7 / 10,11)
//   m=1, q'=3: {bias_hi, bias_lo}, B supplies {1.0, 1.0}
// A lane's OUTPUT units == its own B h-slots -> recurrent h stays in registers;
// its x slots are 2 pre-packed bf16 words read from LDS (staged once/group).
//
// LDS x staging per (step,elem): 8 words = 7 feature pairs (v_cvt_pk_bf16_f32)
// + word7 = 0x3F803F80 (bf16 {1,1} for the bias slots). Lane (q,col) reads
// words {2q, 2q+1} per step with one ds_read_b64.
//
// d_ws: shorts [0..12288): frags ((dir*2+m)*6+tile)*64+lane, 8 shorts.
//   Pre-scaled per gate: i,f,o rows * (-log2e), g rows * (2*log2e).
constexpr float LOG2E    = 1.4426950408889634f;
constexpr float TWOLOG2E = 2.8853900817779268f;
}

#if __has_builtin(__builtin_amdgcn_exp2f)
#define EXP2F(v) __builtin_amdgcn_exp2f(v)
#else
#define EXP2F(v) __expf(0.6931471805599453f * (v))
#endif

__device__ __forceinline__ unsigned short bf16_rne(float f) {
    unsigned int u = __float_as_uint(f);
    u += 0x7fff + ((u >> 16) & 1);
    return (unsigned short)(u >> 16);
}
__device__ __forceinline__ float bf16_to_f(unsigned short s) {
    return __uint_as_float(((unsigned int)s) << 16);
}
__device__ __forceinline__ float fast_rcp(float x) { return __builtin_amdgcn_rcpf(x); }

__global__ void pack_mfma(const float* __restrict__ wif, const float* __restrict__ whf,
                          const float* __restrict__ bif, const float* __restrict__ bhf,
                          const float* __restrict__ wib, const float* __restrict__ whb,
                          const float* __restrict__ bib, const float* __restrict__ bhb,
                          unsigned short* __restrict__ ws)
{
    const int gid = blockIdx.x * 256 + threadIdx.x;
    if (gid >= 1536) return;                 // 2 dir * 2 mfma-sets * 6 tiles * 64 lanes
    const int lane = gid & 63;
    const int tile = (gid >> 6) % 6;
    const int m    = (gid / 384) & 1;        // MFMA index within the step
    const int dir  = gid / 768;
    const int rm = lane & 15, qA = lane >> 4;   // A-frag: row-in-tile, k = qA*8+j
    const int g = (tile < 4) ? tile : (rm & 3);
    const int u_row = (tile < 4) ? rm : ((tile == 4 ? 16 : 20) + (rm >> 2));
    const float* Wx = dir ? wib : wif;
    const float* Wh = dir ? whb : whf;
    const float* bi = dir ? bib : bif;
    const float* bh = dir ? bhb : bhf;
    const int rowW = g * 24 + u_row;         // original weight row
    const float scale = (g == 2) ? TWOLOG2E : -LOG2E;   // g-gate vs i,f,o
    unsigned short vals[8];
    #pragma unroll
    for (int j = 0; j < 8; ++j) {
        unsigned short o;
        if (j < 6) {
            // shared Wh unit map (both MFMAs; m=0 hits h_hi, m=1 hits h_lo)
            const int uh = (j < 4) ? (qA * 4 + j) : ((j == 4 ? 16 : 20) + qA);
            o = bf16_rne(scale * Wh[rowW * H + uh]);
        } else {
            const int jj = j - 6;
            if (m == 0) {
                o = bf16_rne(scale * Wx[rowW * IN_F + 4 * qA + jj]);
            } else if (qA < 3) {
                o = bf16_rne(scale * Wx[rowW * IN_F + 4 * qA + 2 + jj]);
            } else {
                const float b = scale * (bi[rowW] + bh[rowW]);
                const unsigned short hi = bf16_rne(b);
                o = (jj == 0) ? hi : bf16_rne(b - bf16_to_f(hi));
            }
        }
        vals[j] = o;
    }
    unsigned short* d = ws + (size_t)gid * 8;
    #pragma unroll
    for (int j = 0; j < 8; ++j) d[j] = vals[j];
}

// One LSTM step's nonlinear update for 6 units/lane from pre-scaled accs.
// i,f,o hold -a*log2e; g holds 2a*log2e.
// c' = (c*(1+ei)(1+eg) + (eg-1)(1+ef)) * rcp((1+ef)(1+ei)(1+eg))
// h  = (ec-1) * rcp((1+eo)(1+ec)),  ec = exp2(2c'*log2e)
// Outputs the six packed-bf16 h words (hi: uh0..2, lo: ul0..2) that form the
// recurrent B-fragment h slots.
__device__ __forceinline__ void lstm_gates(const f4* acc, f4& cv, float& c_s0, float& c_s1,
                                           f4& Hv, float& h_s0, float& h_s1,
                                           unsigned int& uh0, unsigned int& uh1, unsigned int& uh2,
                                           unsigned int& ul0, unsigned int& ul1, unsigned int& ul2)
{
    f4 EI, EF, EG, EO, EC;
    #pragma unroll
    for (int r = 0; r < 4; ++r) {
        EI[r] = EXP2F(acc[0][r]);
        EF[r] = EXP2F(acc[1][r]);
        EG[r] = EXP2F(acc[2][r]);
        EO[r] = EXP2F(acc[3][r]);
    }
    const f4 P  = (EI + 1.0f) * (EG + 1.0f);
    const f4 Df = P * (EF + 1.0f);
    f4 Rf;
    #pragma unroll
    for (int r = 0; r < 4; ++r) Rf[r] = fast_rcp(Df[r]);
    cv = (cv * P + (EG - 1.0f) * (EF + 1.0f)) * Rf;
    #pragma unroll
    for (int r = 0; r < 4; ++r) EC[r] = EXP2F(TWOLOG2E * cv[r]);
    const f4 Do = (EO + 1.0f) * (EC + 1.0f);
    f4 Ro;
    #pragma unroll
    for (int r = 0; r < 4; ++r) Ro[r] = fast_rcp(Do[r]);
    Hv = (EC - 1.0f) * Ro;

    float hs[2];
    float cs[2] = {c_s0, c_s1};
    #pragma unroll
    for (int s = 0; s < 2; ++s) {
        const float ei = EXP2F(acc[4 + s][0]);
        const float ef = EXP2F(acc[4 + s][1]);
        const float eg = EXP2F(acc[4 + s][2]);
        const float eo = EXP2F(acc[4 + s][3]);
        const float P2 = (1.0f + ei) * (1.0f + eg);
        const float cn = (cs[s] * P2 + (eg - 1.0f) * (1.0f + ef))
                         * fast_rcp(P2 * (1.0f + ef));
        cs[s] = cn;
        const float ec = EXP2F(TWOLOG2E * cn);
        hs[s] = (ec - 1.0f) * fast_rcp((1.0f + eo) * (1.0f + ec));
    }
    c_s0 = cs[0]; c_s1 = cs[1];
    h_s0 = hs[0]; h_s1 = hs[1];

    // pack h -> own B-frag h-slot words {8q+j, j=0..5}: j0..3 = units 4q+j,
    // j4 = 16+q, j5 = 20+q (slots j6,7 carry x and are supplied by the caller)
    f4 Hl;
    #pragma unroll
    for (int r = 0; r < 4; ++r)
        Hl[r] = Hv[r] - __uint_as_float(__float_as_uint(Hv[r]) & 0xFFFF0000u);
    const float hl4 = hs[0] - __uint_as_float(__float_as_uint(hs[0]) & 0xFFFF0000u);
    const float hl5 = hs[1] - __uint_as_float(__float_as_uint(hs[1]) & 0xFFFF0000u);
    uh0 = __builtin_amdgcn_perm(__float_as_uint(Hv[1]), __float_as_uint(Hv[0]), 0x07060302u);
    uh1 = __builtin_amdgcn_perm(__float_as_uint(Hv[3]), __float_as_uint(Hv[2]), 0x07060302u);
    uh2 = __builtin_amdgcn_perm(__float_as_uint(hs[1]), __float_as_uint(hs[0]), 0x07060302u);
    ul0 = __builtin_amdgcn_perm(__float_as_uint(Hl[1]), __float_as_uint(Hl[0]), 0x07060302u);
    ul1 = __builtin_amdgcn_perm(__float_as_uint(Hl[3]), __float_as_uint(Hl[2]), 0x07060302u);
    ul2 = __builtin_amdgcn_perm(__float_as_uint(hl5), __float_as_uint(hl4), 0x07060302u);
}

__global__ __launch_bounds__(128, 4)
void bilstm_mfma(const float* __restrict__ x, const unsigned short* __restrict__ wpk,
                 const float* __restrict__ head_w, const float* __restrict__ head_b,
                 float* __restrict__ out, int B)
{
    // per-wave x staging region (pre-packed bf16 pairs); h-exchange reuses it
    __align__(16) __shared__ unsigned char arena[2 * WAVE_REGION];   // 14 KiB

    const int tid  = threadIdx.x;
    const int wave = __builtin_amdgcn_readfirstlane(tid >> 6);   // 0 = fwd, 1 = bwd
    const int lane = tid & 63;
    const int q    = lane >> 4;
    const int col  = lane & 15;
    const int b0   = blockIdx.x * 16;

    // resident weight A-fragments: 2 MFMA-sets x 6 tiles = 48 VGPRs
    frag8 Aw[2][6];
    #pragma unroll
    for (int m = 0; m < 2; ++m)
        #pragma unroll
        for (int t = 0; t < 6; ++t)
            Aw[m][t] = ((const frag8*)wpk)[((wave * 2 + m) * 6 + t) * 64 + lane];

    unsigned char* xbase = arena + wave * WAVE_REGION;

    // ---- prefill ALL 13 steps: pack x rows to bf16 pairs (wave-private) ----
    // task tau -> (step t = tau>>4, elem e = tau&15); 7 f2 loads (8B-aligned),
    // 7 cvt_pk, 2 ds_write_b128. word7 = bf16{1,1} feeds the bias A-slots.
    for (int tau = lane; tau < NSTEP * 16; tau += 64) {
        const int t = tau >> 4, e = tau & 15;
        const int tt = wave ? (T_STEPS - 1 - t) : t;
        const float* xr = x + ((size_t)(b0 + e) * T_STEPS + tt) * IN_F;
        f2 p[7];
        #pragma unroll
        for (int i = 0; i < 7; ++i) p[i] = *(const f2*)(xr + 2 * i);
        unsigned int w[7];
        #pragma unroll
        for (int i = 0; i < 7; ++i)
            asm("v_cvt_pk_bf16_f32 %0, %1, %2" : "=v"(w[i]) : "v"(p[i].x), "v"(p[i].y));
        unsigned char* d = xbase + t * STEP_B + e * 32;
        *(u4*)d        = (u4){w[0], w[1], w[2], w[3]};
        *(u4*)(d + 16) = (u4){w[4], w[5], w[6], 0x3F803F80u};
    }
    // same-wave DS ops are in-order: no barrier needed before own reads

    const int xoff = col * 32 + q * 8;          // lane's 8-byte pair per step

    f4    cv = {0.f, 0.f, 0.f, 0.f};   // c of units 4q+r
    float c_s0 = 0.f, c_s1 = 0.f;      // c of units 16+q, 20+q
    f4    Hv;                          // h of units 4q+r (fp32, for head)
    float h_s0, h_s1;                  // h of units 16+q, 20+q
    unsigned int uh0 = 0, uh1 = 0, uh2 = 0;   // h_hi words (step 0: h = 0)
    unsigned int ul0 = 0, ul1 = 0, ul2 = 0;   // h_lo words
    const f4 zc = {0.f, 0.f, 0.f, 0.f};

    u2 xw = *(const u2*)(xbase + xoff);        // step-0 x pair

    // ---- steps 0..12: uniform 2-MFMA recurrence, x pair prefetched 1 step ----
    #pragma unroll 1
    for (int s = 0; s < NSTEP; ++s) {
        const u2 xn = *(const u2*)(xbase + (s + 1) * STEP_B + xoff);  // slot 13 = pad
        const frag8 B0 = __builtin_bit_cast(frag8, (u4){uh0, uh1, uh2, xw.x});
        const frag8 B1 = __builtin_bit_cast(frag8, (u4){ul0, ul1, ul2, xw.y});
        f4 acc[6];
        #pragma unroll
        for (int t = 0; t < 6; ++t) {
            acc[t] = __builtin_amdgcn_mfma_f32_16x16x32_bf16(Aw[0][t], B0, zc,     0, 0, 0);
            acc[t] = __builtin_amdgcn_mfma_f32_16x16x32_bf16(Aw[1][t], B1, acc[t], 0, 0, 0);
        }
        lstm_gates(acc, cv, c_s0, c_s1, Hv, h_s0, h_s1, uh0, uh1, uh2, ul0, ul1, ul2);
        xw = xn;
    }

    // final h (fp32) -> own wave region (x staging is dead; in-order DS per wave)
    *(f4*)(xbase + col * 96 + q * 16) = Hv;                       // units 4q+r
    *(float*)(xbase + col * 96 + 64 + q * 4) = h_s0;              // unit 16+q
    *(float*)(xbase + col * 96 + 80 + q * 4) = h_s1;              // unit 20+q

    __syncthreads();   // only cross-wave point: head reads both directions' h

    if (tid < 64) {
        const int e = tid >> 2, cls = tid & 3;
        float acc = head_b[cls];
        const float* hf = (const float*)(arena + e * 96);                  // fwd
        const float* hb = (const float*)(arena + WAVE_REGION + e * 96);    // bwd
        #pragma unroll
        for (int u = 0; u < H; ++u)
            acc += hf[u] * head_w[cls * 2 * H + u] + hb[u] * head_w[cls * 2 * H + H + u];
        out[(size_t)b0 * 4 + tid] = acc;
    }
}

extern "C" void kernel_launch(void* const* d_in, const int* in_sizes, int n_in,
                              void* d_out, int out_size, void* d_ws, size_t ws_size,
                              hipStream_t stream)
{
    const float* x      = (const float*)d_in[0];
    const float* w_ih_f = (const float*)d_in[1];
    const float* w_hh_f = (const float*)d_in[2];
    const float* b_ih_f = (const float*)d_in[3];
    const float* b_hh_f = (const float*)d_in[4];
    const float* w_ih_b = (const float*)d_in[5];
    const float* w_hh_b = (const float*)d_in[6];
    const float* b_ih_b = (const float*)d_in[7];
    const float* b_hh_b = (const float*)d_in[8];
    const float* head_w = (const float*)d_in[9];
    const float* head_b = (const float*)d_in[10];
    float* out = (float*)d_out;
    unsigned short* ws = (unsigned short*)d_ws;

    const int B = in_sizes[0] / (T_STEPS * IN_F);

    hipLaunchKernelGGL(pack_mfma, dim3(6), dim3(256), 0, stream,
                       w_ih_f, w_hh_f, b_ih_f, b_hh_f,
                       w_ih_b, w_hh_b, b_ih_b, b_hh_b, ws);
    hipLaunchKernelGGL(bilstm_mfma, dim3((B + 15) / 16), dim3(128), 0, stream,
                       x, ws, head_w, head_b, out, B);
}

// Round 7
// 168.636 us; speedup vs baseline: 1.0701x; 1.0198x over previous
//
#include <hip/hip_runtime.h>

typedef __attribute__((ext_vector_type(8))) short frag8;     // 8 bf16 = 4 VGPRs
typedef __attribute__((ext_vector_type(4))) float f4;
typedef __attribute__((ext_vector_type(4), aligned(8))) float f4a;  // 8B-aligned loads
typedef __attribute__((ext_vector_type(4))) unsigned int u4;
typedef __attribute__((ext_vector_type(2))) unsigned int u2;
typedef __attribute__((ext_vector_type(2))) float f2;

namespace {
constexpr int T_STEPS = 25;
constexpr int IN_F    = 14;
constexpr int H       = 24;
constexpr int NSTEP   = 13;
constexpr int STEP_B  = 512;               // 16 elems x 8 words x 4 B
constexpr int WAVE_REGION = 14 * STEP_B;   // 13 steps + 1 pad slot (prefetch overrun)
// Pad-free M=96 layout (6 tiles of 16 rows):
//   tile t<4, row m -> gate t, unit m ; tile 4/5 row m -> gate m&3, unit 16/20+(m>>2)
// C/D lane (q=lane>>4, col=lane&15) holds all 4 gates of units
// {4q+r (r=0..3), 16+q, 20+q} = 6 real units.
//
// MERGED 2-MFMA k-map (x folded into the Wh MFMAs' free slots):
// Both MFMAs m=0,1 share the Wh unit map at j=0..5 of each k-group q':
//   j<4 -> unit 4q'+j ; j=4 -> 16+q' ; j=5 -> 20+q'
//   (m=0 multiplies h_hi, m=1 multiplies h_lo; identical Wh weights)
// Slots j=6,7 carry Wx columns (x as single rne-bf16):
//   m=0: features {4q'+0, 4q'+1}
//   m=1, q'<3: features {4q'+2, 4q'+3}
//   m=1, q'=3: {bias_hi, bias_lo}, B supplies {1.0, 1.0}
//
// LDS x staging, LINEAR layout (zero read bank conflicts):
//   step t, pair-index p = q*16+e  ->  byte t*512 + p*8
//   lane l reads its own pair at l*8 (l = q*16+col) with one ds_read_b64.
// Prefill: iteration i stages step t=i; lane l -> chunk c=l&3 of elem e=l>>2.
//   One coalesced 16B load at row+(c==3?40:c*16), 2 cvt_pk, 1 ds_write_b64.
//
// d_ws: shorts [0..12288): frags ((dir*2+m)*6+tile)*64+lane, 8 shorts.
//   Pre-scaled per gate: i,f,o rows * (-log2e), g rows * (2*log2e).
constexpr float LOG2E    = 1.4426950408889634f;
constexpr float TWOLOG2E = 2.8853900817779268f;
}

#if __has_builtin(__builtin_amdgcn_exp2f)
#define EXP2F(v) __builtin_amdgcn_exp2f(v)
#else
#define EXP2F(v) __expf(0.6931471805599453f * (v))
#endif

__device__ __forceinline__ unsigned short bf16_rne(float f) {
    unsigned int u = __float_as_uint(f);
    u += 0x7fff + ((u >> 16) & 1);
    return (unsigned short)(u >> 16);
}
__device__ __forceinline__ float bf16_to_f(unsigned short s) {
    return __uint_as_float(((unsigned int)s) << 16);
}
__device__ __forceinline__ float fast_rcp(float x) { return __builtin_amdgcn_rcpf(x); }

__global__ void pack_mfma(const float* __restrict__ wif, const float* __restrict__ whf,
                          const float* __restrict__ bif, const float* __restrict__ bhf,
                          const float* __restrict__ wib, const float* __restrict__ whb,
                          const float* __restrict__ bib, const float* __restrict__ bhb,
                          unsigned short* __restrict__ ws)
{
    const int gid = blockIdx.x * 256 + threadIdx.x;
    if (gid >= 1536) return;                 // 2 dir * 2 mfma-sets * 6 tiles * 64 lanes
    const int lane = gid & 63;
    const int tile = (gid >> 6) % 6;
    const int m    = (gid / 384) & 1;        // MFMA index within the step
    const int dir  = gid / 768;
    const int rm = lane & 15, qA = lane >> 4;   // A-frag: row-in-tile, k = qA*8+j
    const int g = (tile < 4) ? tile : (rm & 3);
    const int u_row = (tile < 4) ? rm : ((tile == 4 ? 16 : 20) + (rm >> 2));
    const float* Wx = dir ? wib : wif;
    const float* Wh = dir ? whb : whf;
    const float* bi = dir ? bib : bif;
    const float* bh = dir ? bhb : bhf;
    const int rowW = g * 24 + u_row;         // original weight row
    const float scale = (g == 2) ? TWOLOG2E : -LOG2E;   // g-gate vs i,f,o
    unsigned short vals[8];
    #pragma unroll
    for (int j = 0; j < 8; ++j) {
        unsigned short o;
        if (j < 6) {
            // shared Wh unit map (both MFMAs; m=0 hits h_hi, m=1 hits h_lo)
            const int uh = (j < 4) ? (qA * 4 + j) : ((j == 4 ? 16 : 20) + qA);
            o = bf16_rne(scale * Wh[rowW * H + uh]);
        } else {
            const int jj = j - 6;
            if (m == 0) {
                o = bf16_rne(scale * Wx[rowW * IN_F + 4 * qA + jj]);
            } else if (qA < 3) {
                o = bf16_rne(scale * Wx[rowW * IN_F + 4 * qA + 2 + jj]);
            } else {
                const float b = scale * (bi[rowW] + bh[rowW]);
                const unsigned short hi = bf16_rne(b);
                o = (jj == 0) ? hi : bf16_rne(b - bf16_to_f(hi));
            }
        }
        vals[j] = o;
    }
    unsigned short* d = ws + (size_t)gid * 8;
    #pragma unroll
    for (int j = 0; j < 8; ++j) d[j] = vals[j];
}

// One LSTM step's nonlinear update for 6 units/lane from pre-scaled accs.
// i,f,o hold -a*log2e; g holds 2a*log2e.
// c' = (c*(1+ei)(1+eg) + (eg-1)(1+ef)) * rcp((1+ef)(1+ei)(1+eg))
// h  = (ec-1) * rcp((1+eo)(1+ec)),  ec = exp2(2c'*log2e)
// rcp PAIRING: 1/a,1/b via r=rcp(a*b); a_inv=r*b, b_inv=r*a  (12 rcp -> 6).
// Paired products bounded by ~1e26 << fp32 max (needs |preact|>20 to overflow).
__device__ __forceinline__ void lstm_gates(const f4* acc, f4& cv, float& c_s0, float& c_s1,
                                           f4& Hv, float& h_s0, float& h_s1,
                                           unsigned int& uh0, unsigned int& uh1, unsigned int& uh2,
                                           unsigned int& ul0, unsigned int& ul1, unsigned int& ul2)
{
    f4 EI, EF, EG, EO, EC;
    #pragma unroll
    for (int r = 0; r < 4; ++r) {
        EI[r] = EXP2F(acc[0][r]);
        EF[r] = EXP2F(acc[1][r]);
        EG[r] = EXP2F(acc[2][r]);
        EO[r] = EXP2F(acc[3][r]);
    }
    const f4 P  = (EI + 1.0f) * (EG + 1.0f);
    const f4 Df = P * (EF + 1.0f);
    f4 Rf;
    {   // paired rcp: (0,1) and (2,3)
        const float r01 = fast_rcp(Df[0] * Df[1]);
        const float r23 = fast_rcp(Df[2] * Df[3]);
        Rf[0] = r01 * Df[1]; Rf[1] = r01 * Df[0];
        Rf[2] = r23 * Df[3]; Rf[3] = r23 * Df[2];
    }
    cv = (cv * P + (EG - 1.0f) * (EF + 1.0f)) * Rf;
    #pragma unroll
    for (int r = 0; r < 4; ++r) EC[r] = EXP2F(TWOLOG2E * cv[r]);
    const f4 Do = (EO + 1.0f) * (EC + 1.0f);
    f4 Ro;
    {
        const float r01 = fast_rcp(Do[0] * Do[1]);
        const float r23 = fast_rcp(Do[2] * Do[3]);
        Ro[0] = r01 * Do[1]; Ro[1] = r01 * Do[0];
        Ro[2] = r23 * Do[3]; Ro[3] = r23 * Do[2];
    }
    Hv = (EC - 1.0f) * Ro;

    // two scalar units, rcp paired across the two
    float hs[2];
    {
        const float ei0 = EXP2F(acc[4][0]), ef0 = EXP2F(acc[4][1]);
        const float eg0 = EXP2F(acc[4][2]), eo0 = EXP2F(acc[4][3]);
        const float ei1 = EXP2F(acc[5][0]), ef1 = EXP2F(acc[5][1]);
        const float eg1 = EXP2F(acc[5][2]), eo1 = EXP2F(acc[5][3]);
        const float P20 = (1.0f + ei0) * (1.0f + eg0);
        const float P21 = (1.0f + ei1) * (1.0f + eg1);
        const float D0  = P20 * (1.0f + ef0);
        const float D1  = P21 * (1.0f + ef1);
        const float rD  = fast_rcp(D0 * D1);
        const float cn0 = (c_s0 * P20 + (eg0 - 1.0f) * (1.0f + ef0)) * (rD * D1);
        const float cn1 = (c_s1 * P21 + (eg1 - 1.0f) * (1.0f + ef1)) * (rD * D0);
        c_s0 = cn0; c_s1 = cn1;
        const float ec0 = EXP2F(TWOLOG2E * cn0);
        const float ec1 = EXP2F(TWOLOG2E * cn1);
        const float E0  = (1.0f + eo0) * (1.0f + ec0);
        const float E1  = (1.0f + eo1) * (1.0f + ec1);
        const float rE  = fast_rcp(E0 * E1);
        hs[0] = (ec0 - 1.0f) * (rE * E1);
        hs[1] = (ec1 - 1.0f) * (rE * E0);
    }
    h_s0 = hs[0]; h_s1 = hs[1];

    // pack h -> own B-frag h-slot words {8q+j, j=0..5}: j0..3 = units 4q+j,
    // j4 = 16+q, j5 = 20+q (slots j6,7 carry x and are supplied by the caller)
    f4 Hl;
    #pragma unroll
    for (int r = 0; r < 4; ++r)
        Hl[r] = Hv[r] - __uint_as_float(__float_as_uint(Hv[r]) & 0xFFFF0000u);
    const float hl4 = hs[0] - __uint_as_float(__float_as_uint(hs[0]) & 0xFFFF0000u);
    const float hl5 = hs[1] - __uint_as_float(__float_as_uint(hs[1]) & 0xFFFF0000u);
    uh0 = __builtin_amdgcn_perm(__float_as_uint(Hv[1]), __float_as_uint(Hv[0]), 0x07060302u);
    uh1 = __builtin_amdgcn_perm(__float_as_uint(Hv[3]), __float_as_uint(Hv[2]), 0x07060302u);
    uh2 = __builtin_amdgcn_perm(__float_as_uint(hs[1]), __float_as_uint(hs[0]), 0x07060302u);
    ul0 = __builtin_amdgcn_perm(__float_as_uint(Hl[1]), __float_as_uint(Hl[0]), 0x07060302u);
    ul1 = __builtin_amdgcn_perm(__float_as_uint(Hl[3]), __float_as_uint(Hl[2]), 0x07060302u);
    ul2 = __builtin_amdgcn_perm(__float_as_uint(hl5), __float_as_uint(hl4), 0x07060302u);
}

__global__ __launch_bounds__(128, 4)
void bilstm_mfma(const float* __restrict__ x, const unsigned short* __restrict__ wpk,
                 const float* __restrict__ head_w, const float* __restrict__ head_b,
                 float* __restrict__ out, int B)
{
    // per-wave x staging region (pre-packed bf16 pairs); h-exchange reuses it
    __align__(16) __shared__ unsigned char arena[2 * WAVE_REGION];   // 14 KiB

    const int tid  = threadIdx.x;
    const int wave = __builtin_amdgcn_readfirstlane(tid >> 6);   // 0 = fwd, 1 = bwd
    const int lane = tid & 63;
    const int q    = lane >> 4;
    const int col  = lane & 15;
    const int b0   = blockIdx.x * 16;

    // resident weight A-fragments: 2 MFMA-sets x 6 tiles = 48 VGPRs
    frag8 Aw[2][6];
    #pragma unroll
    for (int m = 0; m < 2; ++m)
        #pragma unroll
        for (int t = 0; t < 6; ++t)
            Aw[m][t] = ((const frag8*)wpk)[((wave * 2 + m) * 6 + t) * 64 + lane];

    unsigned char* xbase = arena + wave * WAVE_REGION;

    // ---- prefill: iteration i stages step t=i (coalesced, linear layout) ----
    // lane l -> chunk c = l&3 of elem e = l>>2; 4 lanes/row read contiguous 16B.
    // c<3: features 4c..4c+3 at byte c*16 ; c==3: load byte 40 (f10..f13),
    // use .z,.w (f12,f13), pair word = bf16{1,1} for the bias A-slots.
    {
        const int c  = lane & 3;
        const int e  = lane >> 2;
        const bool c3 = (c == 3);
        const int ldo = c3 ? 40 : c * 16;
        const int woff = (c * 16 + e) * 8;       // pair-index p = c*16+e (linear)
        #pragma unroll 4
        for (int t = 0; t < NSTEP; ++t) {
            const int tt = wave ? (T_STEPS - 1 - t) : t;
            const char* xr = (const char*)x
                           + ((size_t)(b0 + e) * T_STEPS + tt) * (IN_F * 4) + ldo;
            const f4a v = *(const f4a*)xr;       // 8B-aligned 16B load, in-bounds
            unsigned int p0, p1;
            asm("v_cvt_pk_bf16_f32 %0, %1, %2" : "=v"(p0) : "v"(v.x), "v"(v.y));
            asm("v_cvt_pk_bf16_f32 %0, %1, %2" : "=v"(p1) : "v"(v.z), "v"(v.w));
            const unsigned int wa = c3 ? p1 : p0;
            const unsigned int wb = c3 ? 0x3F803F80u : p1;
            *(u2*)(xbase + t * STEP_B + woff) = (u2){wa, wb};
        }
    }
    // same-wave DS ops are in-order: no barrier needed before own reads

    const int xoff = lane * 8;                 // linear: lane's pair, 0 conflicts

    f4    cv = {0.f, 0.f, 0.f, 0.f};   // c of units 4q+r
    float c_s0 = 0.f, c_s1 = 0.f;      // c of units 16+q, 20+q
    f4    Hv;                          // h of units 4q+r (fp32, for head)
    float h_s0, h_s1;                  // h of units 16+q, 20+q
    unsigned int uh0 = 0, uh1 = 0, uh2 = 0;   // h_hi words (step 0: h = 0)
    unsigned int ul0 = 0, ul1 = 0, ul2 = 0;   // h_lo words
    const f4 zc = {0.f, 0.f, 0.f, 0.f};

    u2 xw = *(const u2*)(xbase + xoff);        // step-0 x pair

    // ---- steps 0..12: uniform 2-MFMA recurrence, x pair prefetched 1 step ----
    #pragma unroll 1
    for (int s = 0; s < NSTEP; ++s) {
        const u2 xn = *(const u2*)(xbase + (s + 1) * STEP_B + xoff);  // slot 13 = pad
        const frag8 B0 = __builtin_bit_cast(frag8, (u4){uh0, uh1, uh2, xw.x});
        const frag8 B1 = __builtin_bit_cast(frag8, (u4){ul0, ul1, ul2, xw.y});
        f4 acc[6];
        #pragma unroll
        for (int t = 0; t < 6; ++t) {
            acc[t] = __builtin_amdgcn_mfma_f32_16x16x32_bf16(Aw[0][t], B0, zc,     0, 0, 0);
            acc[t] = __builtin_amdgcn_mfma_f32_16x16x32_bf16(Aw[1][t], B1, acc[t], 0, 0, 0);
        }
        lstm_gates(acc, cv, c_s0, c_s1, Hv, h_s0, h_s1, uh0, uh1, uh2, ul0, ul1, ul2);
        xw = xn;
    }

    // final h (fp32) -> own wave region (x staging is dead; in-order DS per wave)
    *(f4*)(xbase + col * 96 + q * 16) = Hv;                       // units 4q+r
    *(float*)(xbase + col * 96 + 64 + q * 4) = h_s0;              // unit 16+q
    *(float*)(xbase + col * 96 + 80 + q * 4) = h_s1;              // unit 20+q

    __syncthreads();   // only cross-wave point: head reads both directions' h

    if (tid < 64) {
        const int e = tid >> 2, cls = tid & 3;
        float acc = head_b[cls];
        const float* hf = (const float*)(arena + e * 96);                  // fwd
        const float* hb = (const float*)(arena + WAVE_REGION + e * 96);    // bwd
        #pragma unroll
        for (int u = 0; u < H; ++u)
            acc += hf[u] * head_w[cls * 2 * H + u] + hb[u] * head_w[cls * 2 * H + H + u];
        out[(size_t)b0 * 4 + tid] = acc;
    }
}

extern "C" void kernel_launch(void* const* d_in, const int* in_sizes, int n_in,
                              void* d_out, int out_size, void* d_ws, size_t ws_size,
                              hipStream_t stream)
{
    const float* x      = (const float*)d_in[0];
    const float* w_ih_f = (const float*)d_in[1];
    const float* w_hh_f = (const float*)d_in[2];
    const float* b_ih_f = (const float*)d_in[3];
    const float* b_hh_f = (const float*)d_in[4];
    const float* w_ih_b = (const float*)d_in[5];
    const float* w_hh_b = (const float*)d_in[6];
    const float* b_ih_b = (const float*)d_in[7];
    const float* b_hh_b = (const float*)d_in[8];
    const float* head_w = (const float*)d_in[9];
    const float* head_b = (const float*)d_in[10];
    float* out = (float*)d_out;
    unsigned short* ws = (unsigned short*)d_ws;

    const int B = in_sizes[0] / (T_STEPS * IN_F);

    hipLaunchKernelGGL(pack_mfma, dim3(6), dim3(256), 0, stream,
                       w_ih_f, w_hh_f, b_ih_f, b_hh_f,
                       w_ih_b, w_hh_b, b_ih_b, b_hh_b, ws);
    hipLaunchKernelGGL(bilstm_mfma, dim3((B + 15) / 16), dim3(128), 0, stream,
                       x, ws, head_w, head_b, out, B);
}

// Round 8
// 165.931 us; speedup vs baseline: 1.0875x; 1.0163x over previous
//
#include <hip/hip_runtime.h>

typedef __attribute__((ext_vector_type(8))) short frag8;     // 8 bf16 = 4 VGPRs
typedef __attribute__((ext_vector_type(4))) float f4;
typedef __attribute__((ext_vector_type(4), aligned(8))) float f4a;  // 8B-aligned loads
typedef __attribute__((ext_vector_type(4))) unsigned int u4;
typedef __attribute__((ext_vector_type(2))) unsigned int u2;
typedef __attribute__((ext_vector_type(2))) float f2;

namespace {
constexpr int T_STEPS = 25;
constexpr int IN_F    = 14;
constexpr int H       = 24;
constexpr int NSTEP   = 13;
constexpr int STEP_B  = 512;               // 16 elems x 8 words x 4 B
constexpr int WAVE_REGION = 14 * STEP_B;   // 13 steps + 1 pad slot (prefetch overrun)
// M=96 layout (6 tiles of 16 rows):
//   tile t<4, row m -> gate t, unit m      (vector units 0..15)
//   tile 4, row m (r=m&3, qq=m>>2) -> gate r>>1 (i/f),   unit (r&1?20:16)+qq
//   tile 5, row m                  -> gate 2+(r>>1) (g/o), unit (r&1?20:16)+qq
// C/D lane (q=lane>>4, col=lane&15) holds rows m=4q+r ->
//   acc[0..3][r] = gate t of unit 4q+r          (unit-per-component)
//   acc[4] = {i,i,f,f} and acc[5] = {g,g,o,o} of units {16+q, 20+q}
//   (PAIRED layout so the two leftover units run through the same packed-f32
//    gates code as the vector halves.)
//
// MERGED 2-MFMA k-map (x folded into the Wh MFMAs' free slots):
// Both MFMAs m=0,1 share the Wh unit map at j=0..5 of each k-group q':
//   j<4 -> unit 4q'+j ; j=4 -> 16+q' ; j=5 -> 20+q'
//   (m=0 multiplies h_hi, m=1 multiplies h_lo; identical Wh weights)
// Slots j=6,7 carry Wx columns (x as single rne-bf16):
//   m=0: features {4q'+0, 4q'+1}
//   m=1, q'<3: features {4q'+2, 4q'+3}
//   m=1, q'=3: {bias_hi, bias_lo}, B supplies {1.0, 1.0}
//
// LDS x staging, LINEAR layout: step t, pair p -> byte t*512 + p*8;
// lane l reads its pair at l*8 (one ds_read_b64). Prefill: lane l stages
// chunk c=l&3 of elem e=l>>2 (coalesced 16B loads + cvt_pk + ds_write_b64).
//
// d_ws: shorts [0..12288): frags ((dir*2+m)*6+tile)*64+lane, 8 shorts.
//   Pre-scaled per gate: i,f,o rows * (-log2e), g rows * (2*log2e).
//
// Gate math uses PACKED fp32 VALU (v_pk_*_f32 via inline asm): 2 units per
// instruction; running c is kept PRE-SCALED by 2*log2e so EC = exp2(c') with
// no multiply.
constexpr float LOG2E    = 1.4426950408889634f;
constexpr float TWOLOG2E = 2.8853900817779268f;
}

#if __has_builtin(__builtin_amdgcn_exp2f)
#define EXP2F(v) __builtin_amdgcn_exp2f(v)
#else
#define EXP2F(v) __expf(0.6931471805599453f * (v))
#endif

__device__ __forceinline__ unsigned short bf16_rne(float f) {
    unsigned int u = __float_as_uint(f);
    u += 0x7fff + ((u >> 16) & 1);
    return (unsigned short)(u >> 16);
}
__device__ __forceinline__ float bf16_to_f(unsigned short s) {
    return __uint_as_float(((unsigned int)s) << 16);
}
__device__ __forceinline__ float fast_rcp(float x) { return __builtin_amdgcn_rcpf(x); }

// ---- packed fp32 VALU (VOP3P) helpers: 2 floats / instruction ----
__device__ __forceinline__ f2 pk_add(f2 a, f2 b) {
    f2 d; asm("v_pk_add_f32 %0, %1, %2" : "=v"(d) : "v"(a), "v"(b)); return d;
}
__device__ __forceinline__ f2 pk_mul(f2 a, f2 b) {
    f2 d; asm("v_pk_mul_f32 %0, %1, %2" : "=v"(d) : "v"(a), "v"(b)); return d;
}
__device__ __forceinline__ f2 pk_fma(f2 a, f2 b, f2 c) {
    f2 d; asm("v_pk_fma_f32 %0, %1, %2, %3" : "=v"(d) : "v"(a), "v"(b), "v"(c)); return d;
}

__global__ void pack_mfma(const float* __restrict__ wif, const float* __restrict__ whf,
                          const float* __restrict__ bif, const float* __restrict__ bhf,
                          const float* __restrict__ wib, const float* __restrict__ whb,
                          const float* __restrict__ bib, const float* __restrict__ bhb,
                          unsigned short* __restrict__ ws)
{
    const int gid = blockIdx.x * 256 + threadIdx.x;
    if (gid >= 1536) return;                 // 2 dir * 2 mfma-sets * 6 tiles * 64 lanes
    const int lane = gid & 63;
    const int tile = (gid >> 6) % 6;
    const int m    = (gid / 384) & 1;        // MFMA index within the step
    const int dir  = gid / 768;
    const int rm = lane & 15, qA = lane >> 4;   // A-frag: row-in-tile, k = qA*8+j
    int g, u_row;
    if (tile < 4) { g = tile; u_row = rm; }
    else {
        const int r = rm & 3, qq = rm >> 2;   // paired scalar-unit layout (see header)
        g = (tile == 4 ? 0 : 2) + (r >> 1);
        u_row = ((r & 1) ? 20 : 16) + qq;
    }
    const float* Wx = dir ? wib : wif;
    const float* Wh = dir ? whb : whf;
    const float* bi = dir ? bib : bif;
    const float* bh = dir ? bhb : bhf;
    const int rowW = g * 24 + u_row;         // original weight row
    const float scale = (g == 2) ? TWOLOG2E : -LOG2E;   // g-gate vs i,f,o
    unsigned short vals[8];
    #pragma unroll
    for (int j = 0; j < 8; ++j) {
        unsigned short o;
        if (j < 6) {
            // shared Wh unit map (both MFMAs; m=0 hits h_hi, m=1 hits h_lo)
            const int uh = (j < 4) ? (qA * 4 + j) : ((j == 4 ? 16 : 20) + qA);
            o = bf16_rne(scale * Wh[rowW * H + uh]);
        } else {
            const int jj = j - 6;
            if (m == 0) {
                o = bf16_rne(scale * Wx[rowW * IN_F + 4 * qA + jj]);
            } else if (qA < 3) {
                o = bf16_rne(scale * Wx[rowW * IN_F + 4 * qA + 2 + jj]);
            } else {
                const float b = scale * (bi[rowW] + bh[rowW]);
                const unsigned short hi = bf16_rne(b);
                o = (jj == 0) ? hi : bf16_rne(b - bf16_to_f(hi));
            }
        }
        vals[j] = o;
    }
    unsigned short* d = ws + (size_t)gid * 8;
    #pragma unroll
    for (int j = 0; j < 8; ++j) d[j] = vals[j];
}

// One packed pair (2 units) of the LSTM nonlinear update, pre-scaled accs:
// i,f,o hold -a*log2e; g holds 2a*log2e; cvs holds 2*log2e*c (pre-scaled).
// c' = (c*P + (eg-1)(1+ef)) / ((1+ef)*P),  P = (1+ei)(1+eg)
// h  = (ec-1)/((1+eo)(1+ec)),  ec = exp2(cvs')
// rcp paired across the two units: r = rcp(d0*d1); 1/d0 = r*d1, 1/d1 = r*d0.
__device__ __forceinline__ void gates_pair(float ai0, float ai1, float af0, float af1,
                                           float ag0, float ag1, float ao0, float ao1,
                                           f2& cvs, f2& Hp,
                                           f2 ONE, f2 NEGONE, f2 T2L, f2 NT2L)
{
    f2 ei, ef, eg, eo;
    ei.x = EXP2F(ai0); ei.y = EXP2F(ai1);
    ef.x = EXP2F(af0); ef.y = EXP2F(af1);
    eg.x = EXP2F(ag0); eg.y = EXP2F(ag1);
    eo.x = EXP2F(ao0); eo.y = EXP2F(ao1);
    const f2 efp1 = pk_add(ef, ONE);
    const f2 P    = pk_mul(pk_add(ei, ONE), pk_add(eg, ONE));
    const f2 Df   = pk_mul(P, efp1);
    const float r = fast_rcp(Df.x * Df.y);
    f2 Rf; Rf.x = r * Df.y; Rf.y = r * Df.x;
    const f2 X = pk_mul(pk_fma(eg, T2L, NT2L), efp1);   // 2L*(eg-1)*(1+ef)
    cvs = pk_mul(pk_fma(cvs, P, X), Rf);                // pre-scaled c
    f2 ec; ec.x = EXP2F(cvs.x); ec.y = EXP2F(cvs.y);
    const f2 Do = pk_mul(pk_add(eo, ONE), pk_add(ec, ONE));
    const float r2 = fast_rcp(Do.x * Do.y);
    f2 Ro; Ro.x = r2 * Do.y; Ro.y = r2 * Do.x;
    Hp = pk_mul(pk_add(ec, NEGONE), Ro);
}

__device__ __forceinline__ unsigned int perm_hi16(float a_hi, float a_lo) {
    // pack {hi16(a_lo), hi16(a_hi)} with a_lo in the low half (j-even slot)
    return __builtin_amdgcn_perm(__float_as_uint(a_hi), __float_as_uint(a_lo), 0x07060302u);
}

__global__ __launch_bounds__(128, 4)
void bilstm_mfma(const float* __restrict__ x, const unsigned short* __restrict__ wpk,
                 const float* __restrict__ head_w, const float* __restrict__ head_b,
                 float* __restrict__ out, int B)
{
    // per-wave x staging region (pre-packed bf16 pairs); h-exchange reuses it
    __align__(16) __shared__ unsigned char arena[2 * WAVE_REGION];   // 14 KiB

    const int tid  = threadIdx.x;
    const int wave = __builtin_amdgcn_readfirstlane(tid >> 6);   // 0 = fwd, 1 = bwd
    const int lane = tid & 63;
    const int q    = lane >> 4;
    const int col  = lane & 15;
    const int b0   = blockIdx.x * 16;

    // resident weight A-fragments: 2 MFMA-sets x 6 tiles = 48 VGPRs
    frag8 Aw[2][6];
    #pragma unroll
    for (int m = 0; m < 2; ++m)
        #pragma unroll
        for (int t = 0; t < 6; ++t)
            Aw[m][t] = ((const frag8*)wpk)[((wave * 2 + m) * 6 + t) * 64 + lane];

    unsigned char* xbase = arena + wave * WAVE_REGION;

    // ---- prefill: iteration t stages step t (coalesced, linear layout) ----
    // lane l -> chunk c = l&3 of elem e = l>>2; 4 lanes/row read contiguous 16B.
    // c<3: features 4c..4c+3 at byte c*16 ; c==3: load byte 40 (f10..f13),
    // use .z,.w (f12,f13), pair word = bf16{1,1} for the bias A-slots.
    {
        const int c  = lane & 3;
        const int e  = lane >> 2;
        const bool c3 = (c == 3);
        const int ldo = c3 ? 40 : c * 16;
        const int woff = (c * 16 + e) * 8;       // pair-index p = c*16+e (linear)
        #pragma unroll 4
        for (int t = 0; t < NSTEP; ++t) {
            const int tt = wave ? (T_STEPS - 1 - t) : t;
            const char* xr = (const char*)x
                           + ((size_t)(b0 + e) * T_STEPS + tt) * (IN_F * 4) + ldo;
            const f4a v = *(const f4a*)xr;       // 8B-aligned 16B load, in-bounds
            unsigned int p0, p1;
            asm("v_cvt_pk_bf16_f32 %0, %1, %2" : "=v"(p0) : "v"(v.x), "v"(v.y));
            asm("v_cvt_pk_bf16_f32 %0, %1, %2" : "=v"(p1) : "v"(v.z), "v"(v.w));
            const unsigned int wa = c3 ? p1 : p0;
            const unsigned int wb = c3 ? 0x3F803F80u : p1;
            *(u2*)(xbase + t * STEP_B + woff) = (u2){wa, wb};
        }
    }
    // same-wave DS ops are in-order: no barrier needed before own reads

    const int xoff = lane * 8;                 // lane's x pair per step

    // loop-invariant packed constants (hoisted; 8 VGPRs)
    const f2 ONE    = {1.0f, 1.0f};
    const f2 NEGONE = {-1.0f, -1.0f};
    const f2 T2L    = {TWOLOG2E, TWOLOG2E};
    const f2 NT2L   = {-TWOLOG2E, -TWOLOG2E};

    // state: pre-scaled c (2log2e*c) per pair; fp32 h per pair (for head+pack)
    f2 cvl = {0.f, 0.f}, cvh = {0.f, 0.f}, cvs = {0.f, 0.f};
    f2 Hlo, Hhi, Hs;                       // h of units {4q,4q+1},{4q+2,4q+3},{16+q,20+q}
    unsigned int uh0 = 0, uh1 = 0, uh2 = 0;   // h_hi words (step 0: h = 0)
    unsigned int ul0 = 0, ul1 = 0, ul2 = 0;   // h_lo words
    const f4 zc = {0.f, 0.f, 0.f, 0.f};

    u2 xw = *(const u2*)(xbase + xoff);        // step-0 x pair

    // ---- steps 0..12: uniform 2-MFMA recurrence, x pair prefetched 1 step ----
    #pragma unroll 1
    for (int s = 0; s < NSTEP; ++s) {
        const u2 xn = *(const u2*)(xbase + (s + 1) * STEP_B + xoff);  // slot 13 = pad
        const frag8 B0 = __builtin_bit_cast(frag8, (u4){uh0, uh1, uh2, xw.x});
        const frag8 B1 = __builtin_bit_cast(frag8, (u4){ul0, ul1, ul2, xw.y});
        f4 acc[6];
        #pragma unroll
        for (int t = 0; t < 6; ++t) {
            acc[t] = __builtin_amdgcn_mfma_f32_16x16x32_bf16(Aw[0][t], B0, zc,     0, 0, 0);
            acc[t] = __builtin_amdgcn_mfma_f32_16x16x32_bf16(Aw[1][t], B1, acc[t], 0, 0, 0);
        }
        // three packed pairs: units {4q,4q+1}, {4q+2,4q+3}, {16+q,20+q}
        gates_pair(acc[0][0], acc[0][1], acc[1][0], acc[1][1],
                   acc[2][0], acc[2][1], acc[3][0], acc[3][1],
                   cvl, Hlo, ONE, NEGONE, T2L, NT2L);
        gates_pair(acc[0][2], acc[0][3], acc[1][2], acc[1][3],
                   acc[2][2], acc[2][3], acc[3][2], acc[3][3],
                   cvh, Hhi, ONE, NEGONE, T2L, NT2L);
        gates_pair(acc[4][0], acc[4][1], acc[4][2], acc[4][3],
                   acc[5][0], acc[5][1], acc[5][2], acc[5][3],
                   cvs, Hs, ONE, NEGONE, T2L, NT2L);

        // pack h -> B-frag words: hi = trunc16(h), lo = h - hi (hi16 via perm)
        f2 Tl, Th, Ts;
        Tl.x = __uint_as_float(__float_as_uint(Hlo.x) & 0xFFFF0000u);
        Tl.y = __uint_as_float(__float_as_uint(Hlo.y) & 0xFFFF0000u);
        Th.x = __uint_as_float(__float_as_uint(Hhi.x) & 0xFFFF0000u);
        Th.y = __uint_as_float(__float_as_uint(Hhi.y) & 0xFFFF0000u);
        Ts.x = __uint_as_float(__float_as_uint(Hs.x) & 0xFFFF0000u);
        Ts.y = __uint_as_float(__float_as_uint(Hs.y) & 0xFFFF0000u);
        const f2 Ll = pk_fma(Tl, NEGONE, Hlo);
        const f2 Lh = pk_fma(Th, NEGONE, Hhi);
        const f2 Ls = pk_fma(Ts, NEGONE, Hs);
        uh0 = perm_hi16(Hlo.y, Hlo.x); uh1 = perm_hi16(Hhi.y, Hhi.x);
        uh2 = perm_hi16(Hs.y, Hs.x);
        ul0 = perm_hi16(Ll.y, Ll.x);   ul1 = perm_hi16(Lh.y, Lh.x);
        ul2 = perm_hi16(Ls.y, Ls.x);

        xw = xn;
    }

    // final h (fp32) -> own wave region (x staging is dead; in-order DS per wave)
    *(f2*)(xbase + col * 96 + q * 16)     = Hlo;              // units 4q, 4q+1
    *(f2*)(xbase + col * 96 + q * 16 + 8) = Hhi;              // units 4q+2, 4q+3
    *(float*)(xbase + col * 96 + 64 + q * 4) = Hs.x;          // unit 16+q
    *(float*)(xbase + col * 96 + 80 + q * 4) = Hs.y;          // unit 20+q

    __syncthreads();   // only cross-wave point: head reads both directions' h

    if (tid < 64) {
        const int e = tid >> 2, cls = tid & 3;
        float acc = head_b[cls];
        const float* hf = (const float*)(arena + e * 96);                  // fwd
        const float* hb = (const float*)(arena + WAVE_REGION + e * 96);    // bwd
        #pragma unroll
        for (int u = 0; u < H; ++u)
            acc += hf[u] * head_w[cls * 2 * H + u] + hb[u] * head_w[cls * 2 * H + H + u];
        out[(size_t)b0 * 4 + tid] = acc;
    }
}

extern "C" void kernel_launch(void* const* d_in, const int* in_sizes, int n_in,
                              void* d_out, int out_size, void* d_ws, size_t ws_size,
                              hipStream_t stream)
{
    const float* x      = (const float*)d_in[0];
    const float* w_ih_f = (const float*)d_in[1];
    const float* w_hh_f = (const float*)d_in[2];
    const float* b_ih_f = (const float*)d_in[3];
    const float* b_hh_f = (const float*)d_in[4];
    const float* w_ih_b = (const float*)d_in[5];
    const float* w_hh_b = (const float*)d_in[6];
    const float* b_ih_b = (const float*)d_in[7];
    const float* b_hh_b = (const float*)d_in[8];
    const float* head_w = (const float*)d_in[9];
    const float* head_b = (const float*)d_in[10];
    float* out = (float*)d_out;
    unsigned short* ws = (unsigned short*)d_ws;

    const int B = in_sizes[0] / (T_STEPS * IN_F);

    hipLaunchKernelGGL(pack_mfma, dim3(6), dim3(256), 0, stream,
                       w_ih_f, w_hh_f, b_ih_f, b_hh_f,
                       w_ih_b, w_hh_b, b_ih_b, b_hh_b, ws);
    hipLaunchKernelGGL(bilstm_mfma, dim3((B + 15) / 16), dim3(128), 0, stream,
                       x, ws, head_w, head_b, out, B);
}

// Round 9
// 165.734 us; speedup vs baseline: 1.0888x; 1.0012x over previous
//
#include <hip/hip_runtime.h>

typedef __attribute__((ext_vector_type(8))) short frag8;     // 8 bf16 = 4 VGPRs
typedef __attribute__((ext_vector_type(4))) float f4;
typedef __attribute__((ext_vector_type(4), aligned(8))) float f4a;  // 8B-aligned loads
typedef __attribute__((ext_vector_type(4))) unsigned int u4;
typedef __attribute__((ext_vector_type(2))) unsigned int u2;
typedef __attribute__((ext_vector_type(2))) float f2;

namespace {
constexpr int T_STEPS = 25;
constexpr int IN_F    = 14;
constexpr int H       = 24;
constexpr int NSTEP   = 13;
constexpr int STEP_B  = 512;               // 16 elems x 8 words x 4 B
constexpr int WAVE_REGION = 14 * STEP_B;   // 13 steps + 1 pad slot (prefetch overrun)
// 4-WAVE FUSED BLOCK: waves 0,1 = group A (fwd,bwd); waves 2,3 = group B.
// Probes/exploits the observed ~5-resident-blocks/CU cap: if the cap is
// per-block, fusing doubles resident waves/CU.
//
// M=96 layout (6 tiles of 16 rows):
//   tile t<4, row m -> gate t, unit m      (vector units 0..15)
//   tile 4, row m (r=m&3, qq=m>>2) -> gate r>>1 (i/f),   unit (r&1?20:16)+qq
//   tile 5, row m                  -> gate 2+(r>>1) (g/o), unit (r&1?20:16)+qq
// C/D lane (q=lane>>4, col=lane&15) holds rows m=4q+r ->
//   acc[0..3][r] = gate t of unit 4q+r          (unit-per-component)
//   acc[4] = {i,i,f,f} and acc[5] = {g,g,o,o} of units {16+q, 20+q}
//
// MERGED 2-MFMA k-map (x folded into the Wh MFMAs' free slots):
// Both MFMAs m=0,1 share the Wh unit map at j=0..5 of each k-group q':
//   j<4 -> unit 4q'+j ; j=4 -> 16+q' ; j=5 -> 20+q'
//   (m=0 multiplies h_hi, m=1 multiplies h_lo; identical Wh weights)
// Slots j=6,7 carry Wx columns (x as single rne-bf16):
//   m=0: features {4q'+0, 4q'+1}
//   m=1, q'<3: features {4q'+2, 4q'+3}
//   m=1, q'=3: {bias_hi, bias_lo}, B supplies {1.0, 1.0}
//
// LDS x staging, LINEAR layout: step t, pair p -> byte t*512 + p*8;
// lane l reads its pair at l*8 (one ds_read_b64). Prefill: lane l stages
// chunk c=l&3 of elem e=l>>2; TWO-PHASE: all 13 global loads issued
// independently into regs (no vmcnt serialization), then convert+write.
//
// d_ws: shorts [0..12288): frags ((dir*2+m)*6+tile)*64+lane, 8 shorts.
//   Pre-scaled per gate: i,f,o rows * (-log2e), g rows * (2*log2e).
//
// Gate math: packed fp32 (issue-neutral on CDNA4 but fewer instrs) with
// running c PRE-SCALED by 2*log2e so EC = exp2(c') with no multiply.
constexpr float LOG2E    = 1.4426950408889634f;
constexpr float TWOLOG2E = 2.8853900817779268f;
}

#if __has_builtin(__builtin_amdgcn_exp2f)
#define EXP2F(v) __builtin_amdgcn_exp2f(v)
#else
#define EXP2F(v) __expf(0.6931471805599453f * (v))
#endif

__device__ __forceinline__ unsigned short bf16_rne(float f) {
    unsigned int u = __float_as_uint(f);
    u += 0x7fff + ((u >> 16) & 1);
    return (unsigned short)(u >> 16);
}
__device__ __forceinline__ float bf16_to_f(unsigned short s) {
    return __uint_as_float(((unsigned int)s) << 16);
}
__device__ __forceinline__ float fast_rcp(float x) { return __builtin_amdgcn_rcpf(x); }

// ---- packed fp32 VALU (VOP3P) helpers ----
__device__ __forceinline__ f2 pk_add(f2 a, f2 b) {
    f2 d; asm("v_pk_add_f32 %0, %1, %2" : "=v"(d) : "v"(a), "v"(b)); return d;
}
__device__ __forceinline__ f2 pk_mul(f2 a, f2 b) {
    f2 d; asm("v_pk_mul_f32 %0, %1, %2" : "=v"(d) : "v"(a), "v"(b)); return d;
}
__device__ __forceinline__ f2 pk_fma(f2 a, f2 b, f2 c) {
    f2 d; asm("v_pk_fma_f32 %0, %1, %2, %3" : "=v"(d) : "v"(a), "v"(b), "v"(c)); return d;
}

__global__ void pack_mfma(const float* __restrict__ wif, const float* __restrict__ whf,
                          const float* __restrict__ bif, const float* __restrict__ bhf,
                          const float* __restrict__ wib, const float* __restrict__ whb,
                          const float* __restrict__ bib, const float* __restrict__ bhb,
                          unsigned short* __restrict__ ws)
{
    const int gid = blockIdx.x * 256 + threadIdx.x;
    if (gid >= 1536) return;                 // 2 dir * 2 mfma-sets * 6 tiles * 64 lanes
    const int lane = gid & 63;
    const int tile = (gid >> 6) % 6;
    const int m    = (gid / 384) & 1;        // MFMA index within the step
    const int dir  = gid / 768;
    const int rm = lane & 15, qA = lane >> 4;   // A-frag: row-in-tile, k = qA*8+j
    int g, u_row;
    if (tile < 4) { g = tile; u_row = rm; }
    else {
        const int r = rm & 3, qq = rm >> 2;   // paired scalar-unit layout (see header)
        g = (tile == 4 ? 0 : 2) + (r >> 1);
        u_row = ((r & 1) ? 20 : 16) + qq;
    }
    const float* Wx = dir ? wib : wif;
    const float* Wh = dir ? whb : whf;
    const float* bi = dir ? bib : bif;
    const float* bh = dir ? bhb : bhf;
    const int rowW = g * 24 + u_row;         // original weight row
    const float scale = (g == 2) ? TWOLOG2E : -LOG2E;   // g-gate vs i,f,o
    unsigned short vals[8];
    #pragma unroll
    for (int j = 0; j < 8; ++j) {
        unsigned short o;
        if (j < 6) {
            // shared Wh unit map (both MFMAs; m=0 hits h_hi, m=1 hits h_lo)
            const int uh = (j < 4) ? (qA * 4 + j) : ((j == 4 ? 16 : 20) + qA);
            o = bf16_rne(scale * Wh[rowW * H + uh]);
        } else {
            const int jj = j - 6;
            if (m == 0) {
                o = bf16_rne(scale * Wx[rowW * IN_F + 4 * qA + jj]);
            } else if (qA < 3) {
                o = bf16_rne(scale * Wx[rowW * IN_F + 4 * qA + 2 + jj]);
            } else {
                const float b = scale * (bi[rowW] + bh[rowW]);
                const unsigned short hi = bf16_rne(b);
                o = (jj == 0) ? hi : bf16_rne(b - bf16_to_f(hi));
            }
        }
        vals[j] = o;
    }
    unsigned short* d = ws + (size_t)gid * 8;
    #pragma unroll
    for (int j = 0; j < 8; ++j) d[j] = vals[j];
}

// One packed pair (2 units) of the LSTM nonlinear update, pre-scaled accs:
// i,f,o hold -a*log2e; g holds 2a*log2e; cvs holds 2*log2e*c (pre-scaled).
// c' = (c*P + (eg-1)(1+ef)) / ((1+ef)*P),  P = (1+ei)(1+eg)
// h  = (ec-1)/((1+eo)(1+ec)),  ec = exp2(cvs')
// rcp paired across the two units: r = rcp(d0*d1); 1/d0 = r*d1, 1/d1 = r*d0.
__device__ __forceinline__ void gates_pair(float ai0, float ai1, float af0, float af1,
                                           float ag0, float ag1, float ao0, float ao1,
                                           f2& cvs, f2& Hp,
                                           f2 ONE, f2 NEGONE, f2 T2L, f2 NT2L)
{
    f2 ei, ef, eg, eo;
    ei.x = EXP2F(ai0); ei.y = EXP2F(ai1);
    ef.x = EXP2F(af0); ef.y = EXP2F(af1);
    eg.x = EXP2F(ag0); eg.y = EXP2F(ag1);
    eo.x = EXP2F(ao0); eo.y = EXP2F(ao1);
    const f2 efp1 = pk_add(ef, ONE);
    const f2 P    = pk_mul(pk_add(ei, ONE), pk_add(eg, ONE));
    const f2 Df   = pk_mul(P, efp1);
    const float r = fast_rcp(Df.x * Df.y);
    f2 Rf; Rf.x = r * Df.y; Rf.y = r * Df.x;
    const f2 X = pk_mul(pk_fma(eg, T2L, NT2L), efp1);   // 2L*(eg-1)*(1+ef)
    cvs = pk_mul(pk_fma(cvs, P, X), Rf);                // pre-scaled c
    f2 ec; ec.x = EXP2F(cvs.x); ec.y = EXP2F(cvs.y);
    const f2 Do = pk_mul(pk_add(eo, ONE), pk_add(ec, ONE));
    const float r2 = fast_rcp(Do.x * Do.y);
    f2 Ro; Ro.x = r2 * Do.y; Ro.y = r2 * Do.x;
    Hp = pk_mul(pk_add(ec, NEGONE), Ro);
}

__device__ __forceinline__ unsigned int perm_hi16(float a_hi, float a_lo) {
    // pack {hi16(a_lo), hi16(a_hi)} with a_lo in the low half (j-even slot)
    return __builtin_amdgcn_perm(__float_as_uint(a_hi), __float_as_uint(a_lo), 0x07060302u);
}

__global__ __launch_bounds__(256, 4)
void bilstm_mfma(const float* __restrict__ x, const unsigned short* __restrict__ wpk,
                 const float* __restrict__ head_w, const float* __restrict__ head_b,
                 float* __restrict__ out, int B)
{
    // 4 wave-regions: (pair, wave) -> arena + (pair*2+wave)*WAVE_REGION
    __align__(16) __shared__ unsigned char arena[4 * WAVE_REGION];   // 28 KiB

    const int tid  = threadIdx.x;
    const int pr   = __builtin_amdgcn_readfirstlane(tid >> 7);       // pair 0/1
    const int wave = __builtin_amdgcn_readfirstlane((tid >> 6) & 1); // 0 = fwd, 1 = bwd
    const int lane = tid & 63;
    const int q    = lane >> 4;
    const int col  = lane & 15;
    const int nG   = (B + 15) / 16;
    int g = blockIdx.x * 2 + pr;
    if (g >= nG) g = nG - 1;                 // clamp (redundant recompute, benign)
    const int b0   = g * 16;

    // resident weight A-fragments: 2 MFMA-sets x 6 tiles = 48 VGPRs
    frag8 Aw[2][6];
    #pragma unroll
    for (int m = 0; m < 2; ++m)
        #pragma unroll
        for (int t = 0; t < 6; ++t)
            Aw[m][t] = ((const frag8*)wpk)[((wave * 2 + m) * 6 + t) * 64 + lane];

    unsigned char* xbase = arena + (pr * 2 + wave) * WAVE_REGION;

    // ---- prefill, TWO-PHASE (all loads independent, no vmcnt serialization) ----
    // lane l -> chunk c = l&3 of elem e = l>>2; 4 lanes/row read contiguous 16B.
    // c<3: features 4c..4c+3 at byte c*16 ; c==3: load byte 40 (f10..f13),
    // use .z,.w (f12,f13), pair word = bf16{1,1} for the bias A-slots.
    {
        const int c  = lane & 3;
        const int e  = lane >> 2;
        const bool c3 = (c == 3);
        const int ldo = c3 ? 40 : c * 16;
        const int woff = (c * 16 + e) * 8;       // pair-index p = c*16+e (linear)
        const int dstep = wave ? -(IN_F * 4) : (IN_F * 4);
        const char* xcol = (const char*)x
                         + ((size_t)(b0 + e) * T_STEPS + (wave ? T_STEPS - 1 : 0))
                           * (IN_F * 4) + ldo;
        f4a v[NSTEP];
        #pragma unroll
        for (int t = 0; t < NSTEP; ++t)
            v[t] = *(const f4a*)(xcol + t * dstep);   // 13 independent 16B loads
        #pragma unroll
        for (int t = 0; t < NSTEP; ++t) {
            unsigned int p0, p1;
            asm("v_cvt_pk_bf16_f32 %0, %1, %2" : "=v"(p0) : "v"(v[t].x), "v"(v[t].y));
            asm("v_cvt_pk_bf16_f32 %0, %1, %2" : "=v"(p1) : "v"(v[t].z), "v"(v[t].w));
            const unsigned int wa = c3 ? p1 : p0;
            const unsigned int wb = c3 ? 0x3F803F80u : p1;
            *(u2*)(xbase + t * STEP_B + woff) = (u2){wa, wb};
        }
    }
    // same-wave DS ops are in-order: no barrier needed before own reads

    const int xoff = lane * 8;                 // lane's x pair per step

    // loop-invariant packed constants
    const f2 ONE    = {1.0f, 1.0f};
    const f2 NEGONE = {-1.0f, -1.0f};
    const f2 T2L    = {TWOLOG2E, TWOLOG2E};
    const f2 NT2L   = {-TWOLOG2E, -TWOLOG2E};

    // state: pre-scaled c (2log2e*c) per pair; fp32 h per pair (for head+pack)
    f2 cvl = {0.f, 0.f}, cvh = {0.f, 0.f}, cvs = {0.f, 0.f};
    f2 Hlo, Hhi, Hs;                       // h of units {4q,4q+1},{4q+2,4q+3},{16+q,20+q}
    unsigned int uh0 = 0, uh1 = 0, uh2 = 0;   // h_hi words (step 0: h = 0)
    unsigned int ul0 = 0, ul1 = 0, ul2 = 0;   // h_lo words
    const f4 zc = {0.f, 0.f, 0.f, 0.f};

    u2 xw = *(const u2*)(xbase + xoff);        // step-0 x pair

    // ---- steps 0..12: uniform 2-MFMA recurrence, x pair prefetched 1 step ----
    #pragma unroll 1
    for (int s = 0; s < NSTEP; ++s) {
        const u2 xn = *(const u2*)(xbase + (s + 1) * STEP_B + xoff);  // slot 13 = pad
        const frag8 B0 = __builtin_bit_cast(frag8, (u4){uh0, uh1, uh2, xw.x});
        const frag8 B1 = __builtin_bit_cast(frag8, (u4){ul0, ul1, ul2, xw.y});
        f4 acc[6];
        #pragma unroll
        for (int t = 0; t < 6; ++t) {
            acc[t] = __builtin_amdgcn_mfma_f32_16x16x32_bf16(Aw[0][t], B0, zc,     0, 0, 0);
            acc[t] = __builtin_amdgcn_mfma_f32_16x16x32_bf16(Aw[1][t], B1, acc[t], 0, 0, 0);
        }
        // three packed pairs: units {4q,4q+1}, {4q+2,4q+3}, {16+q,20+q}
        gates_pair(acc[0][0], acc[0][1], acc[1][0], acc[1][1],
                   acc[2][0], acc[2][1], acc[3][0], acc[3][1],
                   cvl, Hlo, ONE, NEGONE, T2L, NT2L);
        gates_pair(acc[0][2], acc[0][3], acc[1][2], acc[1][3],
                   acc[2][2], acc[2][3], acc[3][2], acc[3][3],
                   cvh, Hhi, ONE, NEGONE, T2L, NT2L);
        gates_pair(acc[4][0], acc[4][1], acc[4][2], acc[4][3],
                   acc[5][0], acc[5][1], acc[5][2], acc[5][3],
                   cvs, Hs, ONE, NEGONE, T2L, NT2L);

        // pack h -> B-frag words: hi = trunc16(h), lo = h - hi (hi16 via perm)
        f2 Tl, Th, Ts;
        Tl.x = __uint_as_float(__float_as_uint(Hlo.x) & 0xFFFF0000u);
        Tl.y = __uint_as_float(__float_as_uint(Hlo.y) & 0xFFFF0000u);
        Th.x = __uint_as_float(__float_as_uint(Hhi.x) & 0xFFFF0000u);
        Th.y = __uint_as_float(__float_as_uint(Hhi.y) & 0xFFFF0000u);
        Ts.x = __uint_as_float(__float_as_uint(Hs.x) & 0xFFFF0000u);
        Ts.y = __uint_as_float(__float_as_uint(Hs.y) & 0xFFFF0000u);
        const f2 Ll = pk_fma(Tl, NEGONE, Hlo);
        const f2 Lh = pk_fma(Th, NEGONE, Hhi);
        const f2 Ls = pk_fma(Ts, NEGONE, Hs);
        uh0 = perm_hi16(Hlo.y, Hlo.x); uh1 = perm_hi16(Hhi.y, Hhi.x);
        uh2 = perm_hi16(Hs.y, Hs.x);
        ul0 = perm_hi16(Ll.y, Ll.x);   ul1 = perm_hi16(Lh.y, Lh.x);
        ul2 = perm_hi16(Ls.y, Ls.x);

        xw = xn;
    }

    // final h (fp32) -> own wave region (x staging is dead; in-order DS per wave)
    *(f2*)(xbase + col * 96 + q * 16)     = Hlo;              // units 4q, 4q+1
    *(f2*)(xbase + col * 96 + q * 16 + 8) = Hhi;              // units 4q+2, 4q+3
    *(float*)(xbase + col * 96 + 64 + q * 4) = Hs.x;          // unit 16+q
    *(float*)(xbase + col * 96 + 80 + q * 4) = Hs.y;          // unit 20+q

    __syncthreads();   // only cross-wave point: heads read both directions' h

    if (tid < 128) {   // 2 pairs x (16 elems x 4 classes)
        const int pr2 = tid >> 6;
        const int e = (tid & 63) >> 2, cls = tid & 3;
        int g2 = blockIdx.x * 2 + pr2;
        if (g2 >= nG) g2 = nG - 1;
        const unsigned char* region = arena + pr2 * 2 * WAVE_REGION;
        float acc = head_b[cls];
        const float* hf = (const float*)(region + e * 96);                 // fwd
        const float* hb = (const float*)(region + WAVE_REGION + e * 96);   // bwd
        #pragma unroll
        for (int u = 0; u < H; ++u)
            acc += hf[u] * head_w[cls * 2 * H + u] + hb[u] * head_w[cls * 2 * H + H + u];
        out[(size_t)g2 * 64 + (tid & 63)] = acc;
    }
}

extern "C" void kernel_launch(void* const* d_in, const int* in_sizes, int n_in,
                              void* d_out, int out_size, void* d_ws, size_t ws_size,
                              hipStream_t stream)
{
    const float* x      = (const float*)d_in[0];
    const float* w_ih_f = (const float*)d_in[1];
    const float* w_hh_f = (const float*)d_in[2];
    const float* b_ih_f = (const float*)d_in[3];
    const float* b_hh_f = (const float*)d_in[4];
    const float* w_ih_b = (const float*)d_in[5];
    const float* w_hh_b = (const float*)d_in[6];
    const float* b_ih_b = (const float*)d_in[7];
    const float* b_hh_b = (const float*)d_in[8];
    const float* head_w = (const float*)d_in[9];
    const float* head_b = (const float*)d_in[10];
    float* out = (float*)d_out;
    unsigned short* ws = (unsigned short*)d_ws;

    const int B = in_sizes[0] / (T_STEPS * IN_F);
    const int nG = (B + 15) / 16;
    const int nBlk = (nG + 1) / 2;           // 2 groups per 4-wave block

    hipLaunchKernelGGL(pack_mfma, dim3(6), dim3(256), 0, stream,
                       w_ih_f, w_hh_f, b_ih_f, b_hh_f,
                       w_ih_b, w_hh_b, b_ih_b, b_hh_b, ws);
    hipLaunchKernelGGL(bilstm_mfma, dim3(nBlk), dim3(256), 0, stream,
                       x, ws, head_w, head_b, out, B);
}